// Round 13
// baseline (248.072 us; speedup 1.0000x reference)
//
#include <hip/hip_runtime.h>
#include <hip/hip_bf16.h>
#include <math.h>

#define HEADS 4
#define HID 32
#define EMB 32
#define SLOPE 0.2f
#define BN_EPS 1e-5f
#define STATS_BLOCKS 256
#define MB 128     // moment-stats blocks
#define BNUM 256   // bucket array size (actual B = ceil(N/512) <= 256)
#define P 256      // radix blocks

__device__ __forceinline__ float lrelu(float x) { return x > 0.f ? x : SLOPE * x; }
__device__ __forceinline__ float elu(float x) { return x > 0.f ? x : expm1f(x); }

// RNE float->bf16 and pack/unpack helpers
__device__ __forceinline__ unsigned f2bf_pack(float a, float b) {
    unsigned ua = __float_as_uint(a);
    unsigned ub = __float_as_uint(b);
    unsigned ra = (ua + 0x7fffu + ((ua >> 16) & 1u)) >> 16;
    unsigned rb = (ub + 0x7fffu + ((ub >> 16) & 1u)) >> 16;
    return ra | (rb << 16);
}
__device__ __forceinline__ float bf_lo(unsigned p) { return __uint_as_float(p << 16); }
__device__ __forceinline__ float bf_hi(unsigned p) { return __uint_as_float(p & 0xffff0000u); }

// ---------------- tiny prep: Ms[2][4], Md[2][4] = per-head dot(W1 row, attn vec) ----------------
__global__ void k_prep(const float* __restrict__ W1, const float* __restrict__ as1,
                       const float* __restrict__ ad1, float* __restrict__ MsMd) {
    int t = threadIdx.x;
    if (t >= 16) return;
    int r = (t >> 2) & 1, h = t & 3;
    const float* a = (t >= 8) ? ad1 : as1;
    float s = 0.f;
#pragma unroll
    for (int d = 0; d < 32; d++) s += W1[r * 128 + h * 32 + d] * a[h * 32 + d];
    MsMd[t] = s;
}

// ---------------- pass A: per-block histogram, p-major ghist[p][b] ----------------
__global__ void __launch_bounds__(256) k_hist(const int* __restrict__ ei,
                                              int* __restrict__ ghist, int E_, int CH) {
    __shared__ int h[BNUM];
    int t = threadIdx.x, p = blockIdx.x;
    h[t] = 0;
    __syncthreads();
    int beg = p * CH, end = beg + CH;
    if (end > E_) end = E_;
    for (int e = beg + t; e < end; e += 256) atomicAdd(&h[ei[E_ + e] >> 9], 1);
    __syncthreads();
    ghist[p * BNUM + t] = h[t];  // coalesced
}

// ---------------- pass B: exclusive scan of ghist in bucket-major order ----------------
__global__ void __launch_bounds__(1024) k_gscan(const int* __restrict__ ghist,
                                                int* __restrict__ goff, int* __restrict__ sbase,
                                                int* __restrict__ rp, int N_, int E_) {
    __shared__ int s[1024];
    int t = threadIdx.x;
    const int PER = (BNUM * P) / 1024;  // 64
    int b0 = t >> 2;
    int p0 = (t & 3) * PER;
    int v[PER];
    int sum = 0;
#pragma unroll
    for (int k = 0; k < PER; k++) {
        v[k] = ghist[(p0 + k) * BNUM + b0];
        sum += v[k];
    }
    s[t] = sum;
    __syncthreads();
    for (int off = 1; off < 1024; off <<= 1) {
        int a = (t >= off) ? s[t - off] : 0;
        __syncthreads();
        s[t] += a;
        __syncthreads();
    }
    int run = s[t] - sum;
#pragma unroll
    for (int k = 0; k < PER; k++) {
        if (p0 + k == 0) sbase[b0] = run;
        goff[(p0 + k) * BNUM + b0] = run;
        run += v[k];
    }
    if (t == 0) {
        sbase[BNUM] = E_;
        rp[N_] = E_ + N_;
    }
}

// ---------------- pass C: scatter into block-private per-bucket ranges ----------------
__global__ void __launch_bounds__(256) k_scatter3(const int* __restrict__ ei,
                                                  const int* __restrict__ goff,
                                                  unsigned* __restrict__ staged,
                                                  int E_, int CH) {
    __shared__ int loff[BNUM];
    __shared__ int lpos[BNUM];
    int t = threadIdx.x, p = blockIdx.x;
    loff[t] = goff[p * BNUM + t];
    lpos[t] = 0;
    __syncthreads();
    int beg = p * CH, end = beg + CH;
    if (end > E_) end = E_;
    for (int e = beg + t; e < end; e += 256) {
        int s = ei[e], d = ei[E_ + e];
        int b = d >> 9;
        unsigned pk = ((unsigned)s << 9) | (unsigned)(d & 511);
        int pos = loff[b] + atomicAdd(&lpos[b], 1);
        staged[pos] = pk;
    }
}

// ---------------- per-bucket finalize: count, scan, write rp + esrc (+self loops) -------
__global__ void __launch_bounds__(512) k_bucket(const unsigned* __restrict__ staged,
                                                const int* __restrict__ sbase,
                                                int* __restrict__ rp, int* __restrict__ esrc,
                                                int N_) {
    int b = blockIdx.x;
    int n0 = b << 9;
    int nn = N_ - n0;
    if (nn > 512) nn = 512;
    if (nn <= 0) return;
    __shared__ int lc[512];
    __shared__ int sc[512];
    __shared__ int wpos[512];
    int t = threadIdx.x;
    lc[t] = 0;
    __syncthreads();
    int sb = sbase[b];
    int m = sbase[b + 1] - sb;
    int eb = sb + (b << 9);
    for (int i = t; i < m; i += 512) atomicAdd(&lc[staged[sb + i] & 511], 1);
    __syncthreads();
    sc[t] = lc[t];
    __syncthreads();
    for (int off = 1; off < 512; off <<= 1) {
        int a = (t >= off) ? sc[t - off] : 0;
        __syncthreads();
        sc[t] += a;
        __syncthreads();
    }
    if (t < nn) {
        int r = eb + (sc[t] - lc[t]) + t;
        rp[n0 + t] = r;
        wpos[t] = r;
        esrc[r + lc[t]] = n0 + t;          // self loop at final slot (no atomic)
    }
    __syncthreads();
    for (int i = t; i < m; i += 512) {
        unsigned p = staged[sb + i];
        int q = atomicAdd(&wpos[p & 511], 1);
        esrc[q] = (int)(p >> 9);
    }
}

// ---------------- layer 1 aggregation, FACTORIZED: emit only (sx,sy) per head ----------
__global__ void __launch_bounds__(256) k_agg1f(
        const float* __restrict__ x, const int* __restrict__ rp,
        const int* __restrict__ esrc, const float* __restrict__ MsMd,
        float* __restrict__ nsum, int n) {
    __shared__ float sM[16];
    int t = threadIdx.x;
    if (t < 16) sM[t] = MsMd[t];
    __syncthreads();
    int node = blockIdx.x * 64 + (t >> 2);
    int h = t & 3;
    if (node >= n) return;
    int beg = rp[node], end = rp[node + 1];
    const float2 xd = *reinterpret_cast<const float2*>(&x[(size_t)node * 2]);
    float ald = xd.x * sM[8 + h] + xd.y * sM[12 + h];
    float ms0 = sM[h], ms1 = sM[4 + h];
    float z = 0.f, sx = 0.f, sy = 0.f;
#pragma unroll 2
    for (int e = beg; e < end; e++) {
        int s = esrc[e];
        float2 xs = *reinterpret_cast<const float2*>(&x[(size_t)s * 2]);
        float al = xs.x * ms0 + xs.y * ms1;
        float w = __expf(lrelu(al + ald));
        z += w;
        sx = fmaf(w, xs.x, sx);
        sy = fmaf(w, xs.y, sy);
    }
    float inv = 1.f / (z + 1e-16f);
    nsum[(size_t)node * 8 + h] = sx * inv;
    nsum[(size_t)node * 8 + 4 + h] = sy * inv;
}

// ---------------- BN1 moment stats: 5 moments per head over nsum ----------------
__global__ void __launch_bounds__(256) k_mstats(const float* __restrict__ nsum,
                                                float* __restrict__ mpart, int n) {
    int t = threadIdx.x;
    float m[20];
#pragma unroll
    for (int j = 0; j < 20; j++) m[j] = 0.f;
    for (int node = blockIdx.x * 256 + t; node < n; node += gridDim.x * 256) {
        float4 a = *reinterpret_cast<const float4*>(&nsum[(size_t)node * 8]);
        float4 b = *reinterpret_cast<const float4*>(&nsum[(size_t)node * 8 + 4]);
        m[0] += a.x; m[1] += b.x; m[2] += a.x * a.x; m[3] += b.x * b.x; m[4] += a.x * b.x;
        m[5] += a.y; m[6] += b.y; m[7] += a.y * a.y; m[8] += b.y * b.y; m[9] += a.y * b.y;
        m[10] += a.z; m[11] += b.z; m[12] += a.z * a.z; m[13] += b.z * b.z; m[14] += a.z * b.z;
        m[15] += a.w; m[16] += b.w; m[17] += a.w * a.w; m[18] += b.w * b.w; m[19] += a.w * b.w;
    }
#pragma unroll
    for (int off = 1; off < 64; off <<= 1)
#pragma unroll
        for (int j = 0; j < 20; j++) m[j] += __shfl_xor(m[j], off);
    __shared__ float ls[4][20];
    if ((t & 63) == 0)
#pragma unroll
        for (int j = 0; j < 20; j++) ls[t >> 6][j] = m[j];
    __syncthreads();
    if (t < 20) mpart[blockIdx.x * 20 + t] = ls[0][t] + ls[1][t] + ls[2][t] + ls[3][t];
}

// ---------------- BN1 finalize: per-channel P,Q,R  (y = elu(P*sx + Q*sy + R)) ----------
__global__ void k_bn1fin(const float* __restrict__ mpart, const float* __restrict__ W1,
                         const float* __restrict__ b1, const float* __restrict__ g1,
                         const float* __restrict__ be1, float4* __restrict__ PQR,
                         int n, int nb) {
    int c = threadIdx.x;
    if (c >= 128) return;
    int h = c >> 5;
    float mx = 0.f, my = 0.f, mxx = 0.f, myy = 0.f, mxy = 0.f;
    for (int b = 0; b < nb; b++) {
        const float* p = &mpart[b * 20 + h * 5];
        mx += p[0]; my += p[1]; mxx += p[2]; myy += p[3]; mxy += p[4];
    }
    float invn = 1.f / (float)n;
    mx *= invn; my *= invn; mxx *= invn; myy *= invn; mxy *= invn;
    float w0 = W1[c], w1 = W1[128 + c], bb = b1[c];
    float mu = w0 * mx + w1 * my + bb;
    float ex2 = w0 * w0 * mxx + w1 * w1 * myy + 2.f * w0 * w1 * mxy
              + 2.f * bb * (w0 * mx + w1 * my) + bb * bb;
    float var = ex2 - mu * mu;
    float A = g1[c] * rsqrtf(var + BN_EPS);
    float B = be1[c] - mu * A;
    PQR[c] = make_float4(A * w0, A * w1, A * bb + B, 0.f);
}

// ---------------- layer 2 node transform: one thread per node, SCALAR-PATH weights -------
// All W2/PQR indices are thread-independent -> uniformity analysis emits s_load into
// SGPRs (constant cache); FMAs are v_fmac vdst, s_w, v_yk. No LDS, no __syncthreads.
__global__ void __launch_bounds__(256) k_node2s(
        const float* __restrict__ nsum, const float4* __restrict__ PQR,
        const float* __restrict__ W2, const float* __restrict__ as2,
        const float* __restrict__ ad2, unsigned* __restrict__ h2bf,
        float* __restrict__ als2, float* __restrict__ ald2, int n) {
    int node = blockIdx.x * 256 + threadIdx.x;
    if (node >= n) return;
    float4 sx4 = *reinterpret_cast<const float4*>(&nsum[(size_t)node * 8]);
    float4 sy4 = *reinterpret_cast<const float4*>(&nsum[(size_t)node * 8 + 4]);
    float acc[32];
#pragma unroll
    for (int c = 0; c < 32; c++) acc[c] = 0.f;
    float sxh, syh;
#pragma unroll
    for (int h = 0; h < 4; h++) {
        if (h == 0) { sxh = sx4.x; syh = sy4.x; }
        else if (h == 1) { sxh = sx4.y; syh = sy4.y; }
        else if (h == 2) { sxh = sx4.z; syh = sy4.z; }
        else { sxh = sx4.w; syh = sy4.w; }
#pragma unroll 4
        for (int kk = 0; kk < 32; kk++) {
            int k = h * 32 + kk;
            float4 pqr = PQR[k];                 // uniform -> s_load
            float yk = elu(fmaf(pqr.x, sxh, fmaf(pqr.y, syh, pqr.z)));
#pragma unroll
            for (int c = 0; c < 32; c++)
                acc[c] = fmaf(yk, W2[k * 32 + c], acc[c]);   // uniform W2 -> SGPR operand
        }
    }
    float ps = 0.f, pd = 0.f;
#pragma unroll
    for (int c = 0; c < 32; c++) {
        ps = fmaf(acc[c], as2[c], ps);
        pd = fmaf(acc[c], ad2[c], pd);
    }
#pragma unroll
    for (int c = 0; c < 16; c++)
        h2bf[(size_t)node * 16 + c] = f2bf_pack(acc[2 * c], acc[2 * c + 1]);
    als2[node] = ps;
    ald2[node] = pd;
}

// ---------------- BN stats: stage 1 (deterministic tree, float4 loads) ----------------
__global__ void k_stats(const float* __restrict__ x, float* __restrict__ partials,
                        int n, int C) {
    int t = threadIdx.x;
    int G4 = C >> 2;
    int c4 = t & (G4 - 1);
    int rr = t / G4;
    int RPB = 256 / G4;
    float sx = 0.f, sy = 0.f, sz = 0.f, sw_ = 0.f;
    float qx = 0.f, qy = 0.f, qz = 0.f, qw = 0.f;
    for (int r = blockIdx.x * RPB + rr; r < n; r += gridDim.x * RPB) {
        float4 v = *reinterpret_cast<const float4*>(&x[(size_t)r * C + 4 * c4]);
        sx += v.x; sy += v.y; sz += v.z; sw_ += v.w;
        qx += v.x * v.x; qy += v.y * v.y; qz += v.z * v.z; qw += v.w * v.w;
    }
    __shared__ float4 ls[256], ls2[256];
    ls[t] = make_float4(sx, sy, sz, sw_);
    ls2[t] = make_float4(qx, qy, qz, qw);
    __syncthreads();
    if (rr == 0) {
        for (int j = 1; j < RPB; j++) {
            float4 a = ls[j * G4 + c4], b = ls2[j * G4 + c4];
            sx += a.x; sy += a.y; sz += a.z; sw_ += a.w;
            qx += b.x; qy += b.y; qz += b.z; qw += b.w;
        }
        *reinterpret_cast<float4*>(&partials[(size_t)blockIdx.x * 2 * C + 4 * c4]) =
            make_float4(sx, sy, sz, sw_);
        *reinterpret_cast<float4*>(&partials[(size_t)blockIdx.x * 2 * C + C + 4 * c4]) =
            make_float4(qx, qy, qz, qw);
    }
}
// ---------------- BN stats stage 2: parallel finalize (512 threads) ----------------
__global__ void k_stats2(const float* __restrict__ partials, const float* __restrict__ gamma,
                         const float* __restrict__ beta, float* __restrict__ AB,
                         int n, int C, int nb) {
    __shared__ float ls[512], ls2[512];
    int t = threadIdx.x;
    int R = 512 / C;
    int c = t & (C - 1);
    int r = t / C;
    float s = 0.f, s2 = 0.f;
    for (int b = r; b < nb; b += R) {
        s += partials[(size_t)b * 2 * C + c];
        s2 += partials[(size_t)b * 2 * C + C + c];
    }
    ls[t] = s;
    ls2[t] = s2;
    __syncthreads();
    for (int step = R >> 1; step > 0; step >>= 1) {
        if (r < step) {
            ls[t] += ls[t + step * C];
            ls2[t] += ls2[t + step * C];
        }
        __syncthreads();
    }
    if (r == 0) {
        float mu = ls[t] / n;
        float var = ls2[t] / n - mu * mu;
        float inv = rsqrtf(var + BN_EPS);
        float A = gamma[c] * inv;
        AB[c] = A;
        AB[C + c] = beta[c] - mu * A;
    }
}

// ---------------- layer 2 aggregation: 8-lane group per dst node, uint2 bf16 gather -------
__global__ void __launch_bounds__(256) k_agg2(
        const unsigned* __restrict__ h2bf, const float* __restrict__ als2,
        const float* __restrict__ ald2, const int* __restrict__ rp,
        const int* __restrict__ esrc, const float* __restrict__ b2,
        float* __restrict__ out, int n) {
    __shared__ int ss2[4][8][9];    // pad 9 -> group broadcasts on disjoint banks
    __shared__ float swv[4][8][9];
    int wslot = threadIdx.x >> 6;
    int lane = threadIdx.x & 63;
    int g = lane >> 3;       // group within wave
    int e = lane & 7;        // lane within group: dwords 2e,2e+1 of the row
    int wid = blockIdx.x * 32 + wslot * 8 + g;
    if (wid >= n) return;
    int beg = rp[wid], end = rp[wid + 1];
    float ad = ald2[wid];
    float a0 = 0.f, a1 = 0.f, a2 = 0.f, a3 = 0.f;
    float z = 0.f;
    const uint2* __restrict__ hrow = reinterpret_cast<const uint2*>(h2bf);
    for (int cb = beg; cb < end; cb += 8) {
        int cnt = end - cb;
        if (cnt > 8) cnt = 8;
        if (e < cnt) {
            int s = esrc[cb + e];
            ss2[wslot][g][e] = s;
            swv[wslot][g][e] = __expf(lrelu(als2[s] + ad));
        }
        int j = 0;
        for (; j + 4 <= cnt; j += 4) {
            int s0 = ss2[wslot][g][j];
            int s1 = ss2[wslot][g][j + 1];
            int s2 = ss2[wslot][g][j + 2];
            int s3 = ss2[wslot][g][j + 3];
            float w0 = swv[wslot][g][j];
            float w1 = swv[wslot][g][j + 1];
            float w2 = swv[wslot][g][j + 2];
            float w3 = swv[wslot][g][j + 3];
            uint2 p0 = hrow[(size_t)s0 * 8 + e];
            uint2 p1 = hrow[(size_t)s1 * 8 + e];
            uint2 p2 = hrow[(size_t)s2 * 8 + e];
            uint2 p3 = hrow[(size_t)s3 * 8 + e];
            z += w0 + w1 + w2 + w3;
            a0 = fmaf(w0, bf_lo(p0.x), a0); a1 = fmaf(w0, bf_hi(p0.x), a1);
            a2 = fmaf(w0, bf_lo(p0.y), a2); a3 = fmaf(w0, bf_hi(p0.y), a3);
            a0 = fmaf(w1, bf_lo(p1.x), a0); a1 = fmaf(w1, bf_hi(p1.x), a1);
            a2 = fmaf(w1, bf_lo(p1.y), a2); a3 = fmaf(w1, bf_hi(p1.y), a3);
            a0 = fmaf(w2, bf_lo(p2.x), a0); a1 = fmaf(w2, bf_hi(p2.x), a1);
            a2 = fmaf(w2, bf_lo(p2.y), a2); a3 = fmaf(w2, bf_hi(p2.y), a3);
            a0 = fmaf(w3, bf_lo(p3.x), a0); a1 = fmaf(w3, bf_hi(p3.x), a1);
            a2 = fmaf(w3, bf_lo(p3.y), a2); a3 = fmaf(w3, bf_hi(p3.y), a3);
        }
        for (; j < cnt; j++) {
            int s = ss2[wslot][g][j];
            float wgt = swv[wslot][g][j];
            z += wgt;
            uint2 p = hrow[(size_t)s * 8 + e];
            a0 = fmaf(wgt, bf_lo(p.x), a0);
            a1 = fmaf(wgt, bf_hi(p.x), a1);
            a2 = fmaf(wgt, bf_lo(p.y), a2);
            a3 = fmaf(wgt, bf_hi(p.y), a3);
        }
    }
    float inv = 1.f / (z + 1e-16f);   // z uniform across the 8-lane group
    const float4 bv = *reinterpret_cast<const float4*>(&b2[4 * e]);
    float4 o = make_float4(a0 * inv + bv.x, a1 * inv + bv.y, a2 * inv + bv.z, a3 * inv + bv.w);
    *reinterpret_cast<float4*>(&out[(size_t)wid * 32 + 4 * e]) = o;
}

// ---------------- BN2+ELU + mean pool + classifier: wave per graph (inline bounds) -------
__global__ void k_pool(const float* __restrict__ x, const float* __restrict__ AB2,
                       const int* __restrict__ batch, const float* __restrict__ Wc,
                       const float* __restrict__ bc, float* __restrict__ out, int n, int G_) {
    int wid = (blockIdx.x * blockDim.x + threadIdx.x) >> 6;
    int lane = threadIdx.x & 63;
    if (wid >= G_) return;
    int lo = 0, hi = n;
    while (lo < hi) {
        int mid = (lo + hi) >> 1;
        if (batch[mid] < wid) lo = mid + 1; else hi = mid;
    }
    int beg = lo;
    hi = n;
    while (lo < hi) {
        int mid = (lo + hi) >> 1;
        if (batch[mid] < wid + 1) lo = mid + 1; else hi = mid;
    }
    int end = lo;
    int half = lane >> 5, f = lane & 31;
    float A = AB2[f], B = AB2[32 + f];
    float acc = 0.f;
    for (int r = beg + half; r < end; r += 2) {
        float v = x[(size_t)r * 32 + f] * A + B;
        acc += elu(v);
    }
    acc += __shfl_xor(acc, 32);
    float cntf = (float)((end - beg) > 1 ? (end - beg) : 1);
    float embv = acc / cntf;
    float p0 = embv * Wc[f * 2], p1 = embv * Wc[f * 2 + 1];
#pragma unroll
    for (int o = 1; o < 32; o <<= 1) {
        p0 += __shfl_xor(p0, o);
        p1 += __shfl_xor(p1, o);
    }
    if (lane == 0) {
        out[wid * 2] = p0 + bc[0];
        out[wid * 2 + 1] = p1 + bc[1];
    }
}

extern "C" void kernel_launch(void* const* d_in, const int* in_sizes, int n_in,
                              void* d_out, int out_size, void* d_ws, size_t ws_size,
                              hipStream_t stream) {
    const float* x = (const float*)d_in[0];
    const int* ei = (const int*)d_in[1];
    const int* batch = (const int*)d_in[2];
    const float* W1 = (const float*)d_in[3];
    const float* as1 = (const float*)d_in[4];
    const float* ad1 = (const float*)d_in[5];
    const float* b1 = (const float*)d_in[6];
    const float* g1 = (const float*)d_in[7];
    const float* be1 = (const float*)d_in[8];
    const float* W2 = (const float*)d_in[9];
    const float* as2 = (const float*)d_in[10];
    const float* ad2 = (const float*)d_in[11];
    const float* b2 = (const float*)d_in[12];
    const float* g2 = (const float*)d_in[13];
    const float* be2 = (const float*)d_in[14];
    const float* Wc = (const float*)d_in[15];
    const float* bc = (const float*)d_in[16];
    float* out = (float*)d_out;

    const int N = in_sizes[0] / 2;
    const int E = in_sizes[1] / 2;
    const int G = out_size / 2;
    const int Etot = E + N;
    const int B = (N + 511) >> 9;     // buckets of 512 dst nodes (<= 256)
    const int CH = (E + P - 1) / P;   // edges per radix block

    // workspace layout
    char* w = (char*)d_ws;
    size_t off = 0;
    auto alloc = [&](size_t bytes) { void* p = w + off; off = (off + bytes + 255) & ~(size_t)255; return p; };
    float* nsum = (float*)alloc((size_t)N * 8 * 4);          // per-node (sx[4], sy[4])
    unsigned* l2buf = (unsigned*)alloc((size_t)N * 50 * 4);  // h2bf + als2 + ald2 + out2
    int* esrc = (int*)alloc((size_t)Etot * 4);
    unsigned* staged = (unsigned*)alloc((size_t)E * 4);
    int* rp = (int*)alloc((size_t)(N + 1) * 4);
    int* ghist = (int*)alloc((size_t)P * BNUM * 4);
    int* goff = (int*)alloc((size_t)P * BNUM * 4);
    int* sbase = (int*)alloc((BNUM + 1) * 4);
    float* partials = (float*)alloc((size_t)STATS_BLOCKS * 256 * 4);
    float* mpart = (float*)alloc((size_t)MB * 20 * 4);
    float* AB2 = (float*)alloc(64 * 4);
    float* MsMd = (float*)alloc(64 * 4);
    float4* PQR = (float4*)alloc(128 * 16);
    unsigned* h2bf = l2buf;                                  // N*16 uints (N x 32 bf16)
    float* als2 = (float*)(l2buf + (size_t)N * 16);          // N floats
    float* ald2 = (float*)(l2buf + (size_t)N * 17);          // N floats
    float* out2 = (float*)(l2buf + (size_t)N * 18);          // N*32 floats

    // 1. tiny prep: factorized attention matrices
    k_prep<<<1, 64, 0, stream>>>(W1, as1, ad1, MsMd);
    // 2. radix pass A: per-block histograms
    k_hist<<<P, 256, 0, stream>>>(ei, ghist, E, CH);
    // 3. radix pass B: bucket-major exclusive scan -> goff, sbase, rp[N]
    k_gscan<<<1, 1024, 0, stream>>>(ghist, goff, sbase, rp, N, E);
    // 4. radix pass C: scatter to block-private ranges
    k_scatter3<<<P, 256, 0, stream>>>(ei, goff, staged, E, CH);
    // 5. per-bucket finalize: rp + esrc (+self loops)
    k_bucket<<<B, 512, 0, stream>>>(staged, sbase, rp, esrc, N);
    // 6. layer 1 aggregation, factorized: only (sx,sy) per head
    k_agg1f<<<(N + 63) / 64, 256, 0, stream>>>(x, rp, esrc, MsMd, nsum, N);
    // 7. BN1 via per-head moments -> per-channel P,Q,R
    k_mstats<<<MB, 256, 0, stream>>>(nsum, mpart, N);
    k_bn1fin<<<1, 128, 0, stream>>>(mpart, W1, b1, g1, be1, PQR, N, MB);
    // 8. layer 2 node transform: one thread per node, scalar-path weights (no LDS)
    k_node2s<<<(N + 255) / 256, 256, 0, stream>>>(nsum, PQR, W2, as2, ad2, h2bf, als2, ald2, N);
    // 9. layer 2 aggregation (8-lane group per node, 4-edge unroll)
    k_agg2<<<(N + 31) / 32, 256, 0, stream>>>(h2bf, als2, ald2, rp, esrc, b2, out2, N);
    // 10. BN2 stats
    k_stats<<<STATS_BLOCKS, 256, 0, stream>>>(out2, partials, N, 32);
    k_stats2<<<1, 512, 0, stream>>>(partials, g2, be2, AB2, N, 32, STATS_BLOCKS);
    // 11. BN2+ELU + pool + classifier (bounds inline)
    k_pool<<<(G * 64 + 255) / 256, 256, 0, stream>>>(out2, AB2, batch, Wc, bc, out, N, G);
}

// Round 14
// 237.946 us; speedup vs baseline: 1.0426x; 1.0426x over previous
//
#include <hip/hip_runtime.h>
#include <hip/hip_bf16.h>
#include <math.h>

#define HEADS 4
#define HID 32
#define EMB 32
#define SLOPE 0.2f
#define BN_EPS 1e-5f
#define STATS_BLOCKS 256
#define MB 128     // moment-stats blocks
#define BNUM 256   // bucket array size (actual B = ceil(N/512) <= 256)
#define P 256      // radix blocks

__device__ __forceinline__ float lrelu(float x) { return x > 0.f ? x : SLOPE * x; }
__device__ __forceinline__ float elu(float x) { return x > 0.f ? x : expm1f(x); }

// RNE float->bf16 and pack/unpack helpers
__device__ __forceinline__ unsigned f2bf_pack(float a, float b) {
    unsigned ua = __float_as_uint(a);
    unsigned ub = __float_as_uint(b);
    unsigned ra = (ua + 0x7fffu + ((ua >> 16) & 1u)) >> 16;
    unsigned rb = (ub + 0x7fffu + ((ub >> 16) & 1u)) >> 16;
    return ra | (rb << 16);
}
__device__ __forceinline__ float bf_lo(unsigned p) { return __uint_as_float(p << 16); }
__device__ __forceinline__ float bf_hi(unsigned p) { return __uint_as_float(p & 0xffff0000u); }

// ---------------- tiny prep: Ms[2][4], Md[2][4] = per-head dot(W1 row, attn vec) ----------------
__global__ void k_prep(const float* __restrict__ W1, const float* __restrict__ as1,
                       const float* __restrict__ ad1, float* __restrict__ MsMd) {
    int t = threadIdx.x;
    if (t >= 16) return;
    int r = (t >> 2) & 1, h = t & 3;
    const float* a = (t >= 8) ? ad1 : as1;
    float s = 0.f;
#pragma unroll
    for (int d = 0; d < 32; d++) s += W1[r * 128 + h * 32 + d] * a[h * 32 + d];
    MsMd[t] = s;
}

// ---------------- pass A: per-block histogram, p-major ghist[p][b] ----------------
__global__ void __launch_bounds__(256) k_hist(const int* __restrict__ ei,
                                              int* __restrict__ ghist, int E_, int CH) {
    __shared__ int h[BNUM];
    int t = threadIdx.x, p = blockIdx.x;
    h[t] = 0;
    __syncthreads();
    int beg = p * CH, end = beg + CH;
    if (end > E_) end = E_;
    for (int e = beg + t; e < end; e += 256) atomicAdd(&h[ei[E_ + e] >> 9], 1);
    __syncthreads();
    ghist[p * BNUM + t] = h[t];  // coalesced
}

// ---------------- pass B: exclusive scan of ghist in bucket-major order ----------------
__global__ void __launch_bounds__(1024) k_gscan(const int* __restrict__ ghist,
                                                int* __restrict__ goff, int* __restrict__ sbase,
                                                int* __restrict__ rp, int N_, int E_) {
    __shared__ int s[1024];
    int t = threadIdx.x;
    const int PER = (BNUM * P) / 1024;  // 64
    int b0 = t >> 2;
    int p0 = (t & 3) * PER;
    int v[PER];
    int sum = 0;
#pragma unroll
    for (int k = 0; k < PER; k++) {
        v[k] = ghist[(p0 + k) * BNUM + b0];
        sum += v[k];
    }
    s[t] = sum;
    __syncthreads();
    for (int off = 1; off < 1024; off <<= 1) {
        int a = (t >= off) ? s[t - off] : 0;
        __syncthreads();
        s[t] += a;
        __syncthreads();
    }
    int run = s[t] - sum;
#pragma unroll
    for (int k = 0; k < PER; k++) {
        if (p0 + k == 0) sbase[b0] = run;
        goff[(p0 + k) * BNUM + b0] = run;
        run += v[k];
    }
    if (t == 0) {
        sbase[BNUM] = E_;
        rp[N_] = E_ + N_;
    }
}

// ---------------- pass C: scatter into block-private per-bucket ranges ----------------
__global__ void __launch_bounds__(256) k_scatter3(const int* __restrict__ ei,
                                                  const int* __restrict__ goff,
                                                  unsigned* __restrict__ staged,
                                                  int E_, int CH) {
    __shared__ int loff[BNUM];
    __shared__ int lpos[BNUM];
    int t = threadIdx.x, p = blockIdx.x;
    loff[t] = goff[p * BNUM + t];
    lpos[t] = 0;
    __syncthreads();
    int beg = p * CH, end = beg + CH;
    if (end > E_) end = E_;
    for (int e = beg + t; e < end; e += 256) {
        int s = ei[e], d = ei[E_ + e];
        int b = d >> 9;
        unsigned pk = ((unsigned)s << 9) | (unsigned)(d & 511);
        int pos = loff[b] + atomicAdd(&lpos[b], 1);
        staged[pos] = pk;
    }
}

// ---------------- per-bucket finalize: count, scan, write rp + esrc (+self loops) -------
__global__ void __launch_bounds__(512) k_bucket(const unsigned* __restrict__ staged,
                                                const int* __restrict__ sbase,
                                                int* __restrict__ rp, int* __restrict__ esrc,
                                                int N_) {
    int b = blockIdx.x;
    int n0 = b << 9;
    int nn = N_ - n0;
    if (nn > 512) nn = 512;
    if (nn <= 0) return;
    __shared__ int lc[512];
    __shared__ int sc[512];
    __shared__ int wpos[512];
    int t = threadIdx.x;
    lc[t] = 0;
    __syncthreads();
    int sb = sbase[b];
    int m = sbase[b + 1] - sb;
    int eb = sb + (b << 9);
    for (int i = t; i < m; i += 512) atomicAdd(&lc[staged[sb + i] & 511], 1);
    __syncthreads();
    sc[t] = lc[t];
    __syncthreads();
    for (int off = 1; off < 512; off <<= 1) {
        int a = (t >= off) ? sc[t - off] : 0;
        __syncthreads();
        sc[t] += a;
        __syncthreads();
    }
    if (t < nn) {
        int r = eb + (sc[t] - lc[t]) + t;
        rp[n0 + t] = r;
        wpos[t] = r;
        esrc[r + lc[t]] = n0 + t;          // self loop at final slot (no atomic)
    }
    __syncthreads();
    for (int i = t; i < m; i += 512) {
        unsigned p = staged[sb + i];
        int q = atomicAdd(&wpos[p & 511], 1);
        esrc[q] = (int)(p >> 9);
    }
}

// ---------------- layer 1 aggregation, FACTORIZED: emit only (sx,sy) per head ----------
__global__ void __launch_bounds__(256) k_agg1f(
        const float* __restrict__ x, const int* __restrict__ rp,
        const int* __restrict__ esrc, const float* __restrict__ MsMd,
        float* __restrict__ nsum, int n) {
    __shared__ float sM[16];
    int t = threadIdx.x;
    if (t < 16) sM[t] = MsMd[t];
    __syncthreads();
    int node = blockIdx.x * 64 + (t >> 2);
    int h = t & 3;
    if (node >= n) return;
    int beg = rp[node], end = rp[node + 1];
    const float2 xd = *reinterpret_cast<const float2*>(&x[(size_t)node * 2]);
    float ald = xd.x * sM[8 + h] + xd.y * sM[12 + h];
    float ms0 = sM[h], ms1 = sM[4 + h];
    float z = 0.f, sx = 0.f, sy = 0.f;
#pragma unroll 2
    for (int e = beg; e < end; e++) {
        int s = esrc[e];
        float2 xs = *reinterpret_cast<const float2*>(&x[(size_t)s * 2]);
        float al = xs.x * ms0 + xs.y * ms1;
        float w = __expf(lrelu(al + ald));
        z += w;
        sx = fmaf(w, xs.x, sx);
        sy = fmaf(w, xs.y, sy);
    }
    float inv = 1.f / (z + 1e-16f);
    nsum[(size_t)node * 8 + h] = sx * inv;
    nsum[(size_t)node * 8 + 4 + h] = sy * inv;
}

// ---------------- BN1 moment stats: 5 moments per head over nsum ----------------
__global__ void __launch_bounds__(256) k_mstats(const float* __restrict__ nsum,
                                                float* __restrict__ mpart, int n) {
    int t = threadIdx.x;
    float m[20];
#pragma unroll
    for (int j = 0; j < 20; j++) m[j] = 0.f;
    for (int node = blockIdx.x * 256 + t; node < n; node += gridDim.x * 256) {
        float4 a = *reinterpret_cast<const float4*>(&nsum[(size_t)node * 8]);
        float4 b = *reinterpret_cast<const float4*>(&nsum[(size_t)node * 8 + 4]);
        m[0] += a.x; m[1] += b.x; m[2] += a.x * a.x; m[3] += b.x * b.x; m[4] += a.x * b.x;
        m[5] += a.y; m[6] += b.y; m[7] += a.y * a.y; m[8] += b.y * b.y; m[9] += a.y * b.y;
        m[10] += a.z; m[11] += b.z; m[12] += a.z * a.z; m[13] += b.z * b.z; m[14] += a.z * b.z;
        m[15] += a.w; m[16] += b.w; m[17] += a.w * a.w; m[18] += b.w * b.w; m[19] += a.w * b.w;
    }
#pragma unroll
    for (int off = 1; off < 64; off <<= 1)
#pragma unroll
        for (int j = 0; j < 20; j++) m[j] += __shfl_xor(m[j], off);
    __shared__ float ls[4][20];
    if ((t & 63) == 0)
#pragma unroll
        for (int j = 0; j < 20; j++) ls[t >> 6][j] = m[j];
    __syncthreads();
    if (t < 20) mpart[blockIdx.x * 20 + t] = ls[0][t] + ls[1][t] + ls[2][t] + ls[3][t];
}

// ---------------- BN1 finalize: per-channel P,Q,R  (y = elu(P*sx + Q*sy + R)) ----------
__global__ void k_bn1fin(const float* __restrict__ mpart, const float* __restrict__ W1,
                         const float* __restrict__ b1, const float* __restrict__ g1,
                         const float* __restrict__ be1, float4* __restrict__ PQR,
                         int n, int nb) {
    int c = threadIdx.x;
    if (c >= 128) return;
    int h = c >> 5;
    float mx = 0.f, my = 0.f, mxx = 0.f, myy = 0.f, mxy = 0.f;
    for (int b = 0; b < nb; b++) {
        const float* p = &mpart[b * 20 + h * 5];
        mx += p[0]; my += p[1]; mxx += p[2]; myy += p[3]; mxy += p[4];
    }
    float invn = 1.f / (float)n;
    mx *= invn; my *= invn; mxx *= invn; myy *= invn; mxy *= invn;
    float w0 = W1[c], w1 = W1[128 + c], bb = b1[c];
    float mu = w0 * mx + w1 * my + bb;
    float ex2 = w0 * w0 * mxx + w1 * w1 * myy + 2.f * w0 * w1 * mxy
              + 2.f * bb * (w0 * mx + w1 * my) + bb * bb;
    float var = ex2 - mu * mu;
    float A = g1[c] * rsqrtf(var + BN_EPS);
    float B = be1[c] - mu * A;
    PQR[c] = make_float4(A * w0, A * w1, A * bb + B, 0.f);
}

// ---------------- layer 2 node transform: TWO nodes per thread (halves LDS broadcasts) ---
// Round-10 proven LDS-broadcast body; each thread now owns nodes base+t and base+64+t,
// so every ds_read_b128 of W2 feeds 16 FMAs instead of 8. All acc indexing static.
__global__ void __launch_bounds__(64) k_node2f(
        const float* __restrict__ nsum, const float4* __restrict__ PQR,
        const float* __restrict__ W2, const float* __restrict__ as2,
        const float* __restrict__ ad2, unsigned* __restrict__ h2bf,
        float* __restrict__ als2, float* __restrict__ ald2, int n) {
    __shared__ float sw[128 * 32];     // 16 KB
    __shared__ float4 spqr[128];       // 2 KB
    int t = threadIdx.x;
    for (int i = t; i < 128 * 32; i += 64) sw[i] = W2[i];
    for (int i = t; i < 128; i += 64) spqr[i] = PQR[i];
    __syncthreads();
    int node0 = blockIdx.x * 128 + t;
    int node1 = node0 + 64;
    if (node0 >= n) return;
    bool has1 = node1 < n;
    float4 sxa = *reinterpret_cast<const float4*>(&nsum[(size_t)node0 * 8]);
    float4 sya = *reinterpret_cast<const float4*>(&nsum[(size_t)node0 * 8 + 4]);
    float4 sxb = sxa, syb = sya;
    if (has1) {
        sxb = *reinterpret_cast<const float4*>(&nsum[(size_t)node1 * 8]);
        syb = *reinterpret_cast<const float4*>(&nsum[(size_t)node1 * 8 + 4]);
    }
    float accA[32], accB[32];
#pragma unroll
    for (int c = 0; c < 32; c++) { accA[c] = 0.f; accB[c] = 0.f; }
    const float4* sw4 = reinterpret_cast<const float4*>(sw);
    float sxh0, syh0, sxh1, syh1;
#pragma unroll
    for (int h = 0; h < 4; h++) {
        if (h == 0) { sxh0 = sxa.x; syh0 = sya.x; sxh1 = sxb.x; syh1 = syb.x; }
        else if (h == 1) { sxh0 = sxa.y; syh0 = sya.y; sxh1 = sxb.y; syh1 = syb.y; }
        else if (h == 2) { sxh0 = sxa.z; syh0 = sya.z; sxh1 = sxb.z; syh1 = syb.z; }
        else { sxh0 = sxa.w; syh0 = sya.w; sxh1 = sxb.w; syh1 = syb.w; }
        for (int kk = 0; kk < 32; kk++) {
            int k = h * 32 + kk;
            float4 pqr = spqr[k];
            float yk0 = elu(fmaf(pqr.x, sxh0, fmaf(pqr.y, syh0, pqr.z)));
            float yk1 = elu(fmaf(pqr.x, sxh1, fmaf(pqr.y, syh1, pqr.z)));
#pragma unroll
            for (int c4 = 0; c4 < 8; c4++) {
                float4 wv = sw4[k * 8 + c4];
                accA[c4 * 4 + 0] = fmaf(yk0, wv.x, accA[c4 * 4 + 0]);
                accA[c4 * 4 + 1] = fmaf(yk0, wv.y, accA[c4 * 4 + 1]);
                accA[c4 * 4 + 2] = fmaf(yk0, wv.z, accA[c4 * 4 + 2]);
                accA[c4 * 4 + 3] = fmaf(yk0, wv.w, accA[c4 * 4 + 3]);
                accB[c4 * 4 + 0] = fmaf(yk1, wv.x, accB[c4 * 4 + 0]);
                accB[c4 * 4 + 1] = fmaf(yk1, wv.y, accB[c4 * 4 + 1]);
                accB[c4 * 4 + 2] = fmaf(yk1, wv.z, accB[c4 * 4 + 2]);
                accB[c4 * 4 + 3] = fmaf(yk1, wv.w, accB[c4 * 4 + 3]);
            }
        }
    }
    float psA = 0.f, pdA = 0.f, psB = 0.f, pdB = 0.f;
#pragma unroll
    for (int c = 0; c < 32; c++) {
        float a2 = as2[c], d2 = ad2[c];
        psA = fmaf(accA[c], a2, psA);
        pdA = fmaf(accA[c], d2, pdA);
        psB = fmaf(accB[c], a2, psB);
        pdB = fmaf(accB[c], d2, pdB);
    }
#pragma unroll
    for (int c = 0; c < 16; c++)
        h2bf[(size_t)node0 * 16 + c] = f2bf_pack(accA[2 * c], accA[2 * c + 1]);
    als2[node0] = psA;
    ald2[node0] = pdA;
    if (has1) {
#pragma unroll
        for (int c = 0; c < 16; c++)
            h2bf[(size_t)node1 * 16 + c] = f2bf_pack(accB[2 * c], accB[2 * c + 1]);
        als2[node1] = psB;
        ald2[node1] = pdB;
    }
}

// ---------------- BN stats: stage 1 (deterministic tree, float4 loads) ----------------
__global__ void k_stats(const float* __restrict__ x, float* __restrict__ partials,
                        int n, int C) {
    int t = threadIdx.x;
    int G4 = C >> 2;
    int c4 = t & (G4 - 1);
    int rr = t / G4;
    int RPB = 256 / G4;
    float sx = 0.f, sy = 0.f, sz = 0.f, sw_ = 0.f;
    float qx = 0.f, qy = 0.f, qz = 0.f, qw = 0.f;
    for (int r = blockIdx.x * RPB + rr; r < n; r += gridDim.x * RPB) {
        float4 v = *reinterpret_cast<const float4*>(&x[(size_t)r * C + 4 * c4]);
        sx += v.x; sy += v.y; sz += v.z; sw_ += v.w;
        qx += v.x * v.x; qy += v.y * v.y; qz += v.z * v.z; qw += v.w * v.w;
    }
    __shared__ float4 ls[256], ls2[256];
    ls[t] = make_float4(sx, sy, sz, sw_);
    ls2[t] = make_float4(qx, qy, qz, qw);
    __syncthreads();
    if (rr == 0) {
        for (int j = 1; j < RPB; j++) {
            float4 a = ls[j * G4 + c4], b = ls2[j * G4 + c4];
            sx += a.x; sy += a.y; sz += a.z; sw_ += a.w;
            qx += b.x; qy += b.y; qz += b.z; qw += b.w;
        }
        *reinterpret_cast<float4*>(&partials[(size_t)blockIdx.x * 2 * C + 4 * c4]) =
            make_float4(sx, sy, sz, sw_);
        *reinterpret_cast<float4*>(&partials[(size_t)blockIdx.x * 2 * C + C + 4 * c4]) =
            make_float4(qx, qy, qz, qw);
    }
}
// ---------------- BN stats stage 2: parallel finalize (512 threads) ----------------
__global__ void k_stats2(const float* __restrict__ partials, const float* __restrict__ gamma,
                         const float* __restrict__ beta, float* __restrict__ AB,
                         int n, int C, int nb) {
    __shared__ float ls[512], ls2[512];
    int t = threadIdx.x;
    int R = 512 / C;
    int c = t & (C - 1);
    int r = t / C;
    float s = 0.f, s2 = 0.f;
    for (int b = r; b < nb; b += R) {
        s += partials[(size_t)b * 2 * C + c];
        s2 += partials[(size_t)b * 2 * C + C + c];
    }
    ls[t] = s;
    ls2[t] = s2;
    __syncthreads();
    for (int step = R >> 1; step > 0; step >>= 1) {
        if (r < step) {
            ls[t] += ls[t + step * C];
            ls2[t] += ls2[t + step * C];
        }
        __syncthreads();
    }
    if (r == 0) {
        float mu = ls[t] / n;
        float var = ls2[t] / n - mu * mu;
        float inv = rsqrtf(var + BN_EPS);
        float A = gamma[c] * inv;
        AB[c] = A;
        AB[C + c] = beta[c] - mu * A;
    }
}

// ---------------- layer 2 aggregation: 8-lane group per dst node, uint2 bf16 gather -------
__global__ void __launch_bounds__(256) k_agg2(
        const unsigned* __restrict__ h2bf, const float* __restrict__ als2,
        const float* __restrict__ ald2, const int* __restrict__ rp,
        const int* __restrict__ esrc, const float* __restrict__ b2,
        float* __restrict__ out, int n) {
    __shared__ int ss2[4][8][9];    // pad 9 -> group broadcasts on disjoint banks
    __shared__ float swv[4][8][9];
    int wslot = threadIdx.x >> 6;
    int lane = threadIdx.x & 63;
    int g = lane >> 3;       // group within wave
    int e = lane & 7;        // lane within group: dwords 2e,2e+1 of the row
    int wid = blockIdx.x * 32 + wslot * 8 + g;
    if (wid >= n) return;
    int beg = rp[wid], end = rp[wid + 1];
    float ad = ald2[wid];
    float a0 = 0.f, a1 = 0.f, a2 = 0.f, a3 = 0.f;
    float z = 0.f;
    const uint2* __restrict__ hrow = reinterpret_cast<const uint2*>(h2bf);
    for (int cb = beg; cb < end; cb += 8) {
        int cnt = end - cb;
        if (cnt > 8) cnt = 8;
        if (e < cnt) {
            int s = esrc[cb + e];
            ss2[wslot][g][e] = s;
            swv[wslot][g][e] = __expf(lrelu(als2[s] + ad));
        }
        int j = 0;
        for (; j + 4 <= cnt; j += 4) {
            int s0 = ss2[wslot][g][j];
            int s1 = ss2[wslot][g][j + 1];
            int s2 = ss2[wslot][g][j + 2];
            int s3 = ss2[wslot][g][j + 3];
            float w0 = swv[wslot][g][j];
            float w1 = swv[wslot][g][j + 1];
            float w2 = swv[wslot][g][j + 2];
            float w3 = swv[wslot][g][j + 3];
            uint2 p0 = hrow[(size_t)s0 * 8 + e];
            uint2 p1 = hrow[(size_t)s1 * 8 + e];
            uint2 p2 = hrow[(size_t)s2 * 8 + e];
            uint2 p3 = hrow[(size_t)s3 * 8 + e];
            z += w0 + w1 + w2 + w3;
            a0 = fmaf(w0, bf_lo(p0.x), a0); a1 = fmaf(w0, bf_hi(p0.x), a1);
            a2 = fmaf(w0, bf_lo(p0.y), a2); a3 = fmaf(w0, bf_hi(p0.y), a3);
            a0 = fmaf(w1, bf_lo(p1.x), a0); a1 = fmaf(w1, bf_hi(p1.x), a1);
            a2 = fmaf(w1, bf_lo(p1.y), a2); a3 = fmaf(w1, bf_hi(p1.y), a3);
            a0 = fmaf(w2, bf_lo(p2.x), a0); a1 = fmaf(w2, bf_hi(p2.x), a1);
            a2 = fmaf(w2, bf_lo(p2.y), a2); a3 = fmaf(w2, bf_hi(p2.y), a3);
            a0 = fmaf(w3, bf_lo(p3.x), a0); a1 = fmaf(w3, bf_hi(p3.x), a1);
            a2 = fmaf(w3, bf_lo(p3.y), a2); a3 = fmaf(w3, bf_hi(p3.y), a3);
        }
        for (; j < cnt; j++) {
            int s = ss2[wslot][g][j];
            float wgt = swv[wslot][g][j];
            z += wgt;
            uint2 p = hrow[(size_t)s * 8 + e];
            a0 = fmaf(wgt, bf_lo(p.x), a0);
            a1 = fmaf(wgt, bf_hi(p.x), a1);
            a2 = fmaf(wgt, bf_lo(p.y), a2);
            a3 = fmaf(wgt, bf_hi(p.y), a3);
        }
    }
    float inv = 1.f / (z + 1e-16f);   // z uniform across the 8-lane group
    const float4 bv = *reinterpret_cast<const float4*>(&b2[4 * e]);
    float4 o = make_float4(a0 * inv + bv.x, a1 * inv + bv.y, a2 * inv + bv.z, a3 * inv + bv.w);
    *reinterpret_cast<float4*>(&out[(size_t)wid * 32 + 4 * e]) = o;
}

// ---------------- BN2+ELU + mean pool + classifier: wave per graph (inline bounds) -------
__global__ void k_pool(const float* __restrict__ x, const float* __restrict__ AB2,
                       const int* __restrict__ batch, const float* __restrict__ Wc,
                       const float* __restrict__ bc, float* __restrict__ out, int n, int G_) {
    int wid = (blockIdx.x * blockDim.x + threadIdx.x) >> 6;
    int lane = threadIdx.x & 63;
    if (wid >= G_) return;
    int lo = 0, hi = n;
    while (lo < hi) {
        int mid = (lo + hi) >> 1;
        if (batch[mid] < wid) lo = mid + 1; else hi = mid;
    }
    int beg = lo;
    hi = n;
    while (lo < hi) {
        int mid = (lo + hi) >> 1;
        if (batch[mid] < wid + 1) lo = mid + 1; else hi = mid;
    }
    int end = lo;
    int half = lane >> 5, f = lane & 31;
    float A = AB2[f], B = AB2[32 + f];
    float acc = 0.f;
    for (int r = beg + half; r < end; r += 2) {
        float v = x[(size_t)r * 32 + f] * A + B;
        acc += elu(v);
    }
    acc += __shfl_xor(acc, 32);
    float cntf = (float)((end - beg) > 1 ? (end - beg) : 1);
    float embv = acc / cntf;
    float p0 = embv * Wc[f * 2], p1 = embv * Wc[f * 2 + 1];
#pragma unroll
    for (int o = 1; o < 32; o <<= 1) {
        p0 += __shfl_xor(p0, o);
        p1 += __shfl_xor(p1, o);
    }
    if (lane == 0) {
        out[wid * 2] = p0 + bc[0];
        out[wid * 2 + 1] = p1 + bc[1];
    }
}

extern "C" void kernel_launch(void* const* d_in, const int* in_sizes, int n_in,
                              void* d_out, int out_size, void* d_ws, size_t ws_size,
                              hipStream_t stream) {
    const float* x = (const float*)d_in[0];
    const int* ei = (const int*)d_in[1];
    const int* batch = (const int*)d_in[2];
    const float* W1 = (const float*)d_in[3];
    const float* as1 = (const float*)d_in[4];
    const float* ad1 = (const float*)d_in[5];
    const float* b1 = (const float*)d_in[6];
    const float* g1 = (const float*)d_in[7];
    const float* be1 = (const float*)d_in[8];
    const float* W2 = (const float*)d_in[9];
    const float* as2 = (const float*)d_in[10];
    const float* ad2 = (const float*)d_in[11];
    const float* b2 = (const float*)d_in[12];
    const float* g2 = (const float*)d_in[13];
    const float* be2 = (const float*)d_in[14];
    const float* Wc = (const float*)d_in[15];
    const float* bc = (const float*)d_in[16];
    float* out = (float*)d_out;

    const int N = in_sizes[0] / 2;
    const int E = in_sizes[1] / 2;
    const int G = out_size / 2;
    const int Etot = E + N;
    const int B = (N + 511) >> 9;     // buckets of 512 dst nodes (<= 256)
    const int CH = (E + P - 1) / P;   // edges per radix block

    // workspace layout
    char* w = (char*)d_ws;
    size_t off = 0;
    auto alloc = [&](size_t bytes) { void* p = w + off; off = (off + bytes + 255) & ~(size_t)255; return p; };
    float* nsum = (float*)alloc((size_t)N * 8 * 4);          // per-node (sx[4], sy[4])
    unsigned* l2buf = (unsigned*)alloc((size_t)N * 50 * 4);  // h2bf + als2 + ald2 + out2
    int* esrc = (int*)alloc((size_t)Etot * 4);
    unsigned* staged = (unsigned*)alloc((size_t)E * 4);
    int* rp = (int*)alloc((size_t)(N + 1) * 4);
    int* ghist = (int*)alloc((size_t)P * BNUM * 4);
    int* goff = (int*)alloc((size_t)P * BNUM * 4);
    int* sbase = (int*)alloc((BNUM + 1) * 4);
    float* partials = (float*)alloc((size_t)STATS_BLOCKS * 256 * 4);
    float* mpart = (float*)alloc((size_t)MB * 20 * 4);
    float* AB2 = (float*)alloc(64 * 4);
    float* MsMd = (float*)alloc(64 * 4);
    float4* PQR = (float4*)alloc(128 * 16);
    unsigned* h2bf = l2buf;                                  // N*16 uints (N x 32 bf16)
    float* als2 = (float*)(l2buf + (size_t)N * 16);          // N floats
    float* ald2 = (float*)(l2buf + (size_t)N * 17);          // N floats
    float* out2 = (float*)(l2buf + (size_t)N * 18);          // N*32 floats

    // 1. tiny prep: factorized attention matrices
    k_prep<<<1, 64, 0, stream>>>(W1, as1, ad1, MsMd);
    // 2. radix pass A: per-block histograms
    k_hist<<<P, 256, 0, stream>>>(ei, ghist, E, CH);
    // 3. radix pass B: bucket-major exclusive scan -> goff, sbase, rp[N]
    k_gscan<<<1, 1024, 0, stream>>>(ghist, goff, sbase, rp, N, E);
    // 4. radix pass C: scatter to block-private ranges
    k_scatter3<<<P, 256, 0, stream>>>(ei, goff, staged, E, CH);
    // 5. per-bucket finalize: rp + esrc (+self loops)
    k_bucket<<<B, 512, 0, stream>>>(staged, sbase, rp, esrc, N);
    // 6. layer 1 aggregation, factorized: only (sx,sy) per head
    k_agg1f<<<(N + 63) / 64, 256, 0, stream>>>(x, rp, esrc, MsMd, nsum, N);
    // 7. BN1 via per-head moments -> per-channel P,Q,R
    k_mstats<<<MB, 256, 0, stream>>>(nsum, mpart, N);
    k_bn1fin<<<1, 128, 0, stream>>>(mpart, W1, b1, g1, be1, PQR, N, MB);
    // 8. layer 2 node transform: two nodes per thread, 64-thread blocks
    k_node2f<<<(N + 127) / 128, 64, 0, stream>>>(nsum, PQR, W2, as2, ad2, h2bf, als2, ald2, N);
    // 9. layer 2 aggregation (8-lane group per node, 4-edge unroll)
    k_agg2<<<(N + 31) / 32, 256, 0, stream>>>(h2bf, als2, ald2, rp, esrc, b2, out2, N);
    // 10. BN2 stats
    k_stats<<<STATS_BLOCKS, 256, 0, stream>>>(out2, partials, N, 32);
    k_stats2<<<1, 512, 0, stream>>>(partials, g2, be2, AB2, N, 32, STATS_BLOCKS);
    // 11. BN2+ELU + pool + classifier (bounds inline)
    k_pool<<<(G * 64 + 255) / 256, 256, 0, stream>>>(out2, AB2, batch, Wc, bc, out, N, G);
}

// Round 15
// 230.075 us; speedup vs baseline: 1.0782x; 1.0342x over previous
//
#include <hip/hip_runtime.h>
#include <hip/hip_bf16.h>
#include <math.h>

#define HEADS 4
#define HID 32
#define EMB 32
#define SLOPE 0.2f
#define BN_EPS 1e-5f
#define STATS_BLOCKS 256
#define MB 128     // moment-stats blocks
#define BNUM 256   // bucket array size (actual B = ceil(N/512) <= 256)
#define P 256      // radix blocks

__device__ __forceinline__ float lrelu(float x) { return x > 0.f ? x : SLOPE * x; }
__device__ __forceinline__ float elu(float x) { return x > 0.f ? x : expm1f(x); }

// RNE float->bf16 and pack/unpack helpers
__device__ __forceinline__ unsigned f2bf_pack(float a, float b) {
    unsigned ua = __float_as_uint(a);
    unsigned ub = __float_as_uint(b);
    unsigned ra = (ua + 0x7fffu + ((ua >> 16) & 1u)) >> 16;
    unsigned rb = (ub + 0x7fffu + ((ub >> 16) & 1u)) >> 16;
    return ra | (rb << 16);
}
__device__ __forceinline__ float bf_lo(unsigned p) { return __uint_as_float(p << 16); }
__device__ __forceinline__ float bf_hi(unsigned p) { return __uint_as_float(p & 0xffff0000u); }

// ---------------- tiny prep: Ms[2][4], Md[2][4] = per-head dot(W1 row, attn vec) ----------------
__global__ void k_prep(const float* __restrict__ W1, const float* __restrict__ as1,
                       const float* __restrict__ ad1, float* __restrict__ MsMd) {
    int t = threadIdx.x;
    if (t >= 16) return;
    int r = (t >> 2) & 1, h = t & 3;
    const float* a = (t >= 8) ? ad1 : as1;
    float s = 0.f;
#pragma unroll
    for (int d = 0; d < 32; d++) s += W1[r * 128 + h * 32 + d] * a[h * 32 + d];
    MsMd[t] = s;
}

// ---------------- tiny prep: pack W2 into bf16 channel-pairs ----------------
__global__ void k_packW2(const float* __restrict__ W2, unsigned* __restrict__ W2bf) {
    int i = blockIdx.x * 256 + threadIdx.x;
    if (i < 2048) W2bf[i] = f2bf_pack(W2[2 * i], W2[2 * i + 1]);
}

// ---------------- pass A: per-block histogram, p-major ghist[p][b] ----------------
__global__ void __launch_bounds__(256) k_hist(const int* __restrict__ ei,
                                              int* __restrict__ ghist, int E_, int CH) {
    __shared__ int h[BNUM];
    int t = threadIdx.x, p = blockIdx.x;
    h[t] = 0;
    __syncthreads();
    int beg = p * CH, end = beg + CH;
    if (end > E_) end = E_;
    for (int e = beg + t; e < end; e += 256) atomicAdd(&h[ei[E_ + e] >> 9], 1);
    __syncthreads();
    ghist[p * BNUM + t] = h[t];  // coalesced
}

// ---------------- pass B: exclusive scan of ghist in bucket-major order ----------------
__global__ void __launch_bounds__(1024) k_gscan(const int* __restrict__ ghist,
                                                int* __restrict__ goff, int* __restrict__ sbase,
                                                int* __restrict__ rp, int N_, int E_) {
    __shared__ int s[1024];
    int t = threadIdx.x;
    const int PER = (BNUM * P) / 1024;  // 64
    int b0 = t >> 2;
    int p0 = (t & 3) * PER;
    int v[PER];
    int sum = 0;
#pragma unroll
    for (int k = 0; k < PER; k++) {
        v[k] = ghist[(p0 + k) * BNUM + b0];
        sum += v[k];
    }
    s[t] = sum;
    __syncthreads();
    for (int off = 1; off < 1024; off <<= 1) {
        int a = (t >= off) ? s[t - off] : 0;
        __syncthreads();
        s[t] += a;
        __syncthreads();
    }
    int run = s[t] - sum;
#pragma unroll
    for (int k = 0; k < PER; k++) {
        if (p0 + k == 0) sbase[b0] = run;
        goff[(p0 + k) * BNUM + b0] = run;
        run += v[k];
    }
    if (t == 0) {
        sbase[BNUM] = E_;
        rp[N_] = E_ + N_;
    }
}

// ---------------- pass C: scatter into block-private per-bucket ranges ----------------
__global__ void __launch_bounds__(256) k_scatter3(const int* __restrict__ ei,
                                                  const int* __restrict__ goff,
                                                  unsigned* __restrict__ staged,
                                                  int E_, int CH) {
    __shared__ int loff[BNUM];
    __shared__ int lpos[BNUM];
    int t = threadIdx.x, p = blockIdx.x;
    loff[t] = goff[p * BNUM + t];
    lpos[t] = 0;
    __syncthreads();
    int beg = p * CH, end = beg + CH;
    if (end > E_) end = E_;
    for (int e = beg + t; e < end; e += 256) {
        int s = ei[e], d = ei[E_ + e];
        int b = d >> 9;
        unsigned pk = ((unsigned)s << 9) | (unsigned)(d & 511);
        int pos = loff[b] + atomicAdd(&lpos[b], 1);
        staged[pos] = pk;
    }
}

// ---------------- per-bucket finalize: count, scan, write rp + esrc (+self loops) -------
__global__ void __launch_bounds__(512) k_bucket(const unsigned* __restrict__ staged,
                                                const int* __restrict__ sbase,
                                                int* __restrict__ rp, int* __restrict__ esrc,
                                                int N_) {
    int b = blockIdx.x;
    int n0 = b << 9;
    int nn = N_ - n0;
    if (nn > 512) nn = 512;
    if (nn <= 0) return;
    __shared__ int lc[512];
    __shared__ int sc[512];
    __shared__ int wpos[512];
    int t = threadIdx.x;
    lc[t] = 0;
    __syncthreads();
    int sb = sbase[b];
    int m = sbase[b + 1] - sb;
    int eb = sb + (b << 9);
    for (int i = t; i < m; i += 512) atomicAdd(&lc[staged[sb + i] & 511], 1);
    __syncthreads();
    sc[t] = lc[t];
    __syncthreads();
    for (int off = 1; off < 512; off <<= 1) {
        int a = (t >= off) ? sc[t - off] : 0;
        __syncthreads();
        sc[t] += a;
        __syncthreads();
    }
    if (t < nn) {
        int r = eb + (sc[t] - lc[t]) + t;
        rp[n0 + t] = r;
        wpos[t] = r;
        esrc[r + lc[t]] = n0 + t;          // self loop at final slot (no atomic)
    }
    __syncthreads();
    for (int i = t; i < m; i += 512) {
        unsigned p = staged[sb + i];
        int q = atomicAdd(&wpos[p & 511], 1);
        esrc[q] = (int)(p >> 9);
    }
}

// ---------------- layer 1 aggregation, FACTORIZED: emit only (sx,sy) per head ----------
__global__ void __launch_bounds__(256) k_agg1f(
        const float* __restrict__ x, const int* __restrict__ rp,
        const int* __restrict__ esrc, const float* __restrict__ MsMd,
        float* __restrict__ nsum, int n) {
    __shared__ float sM[16];
    int t = threadIdx.x;
    if (t < 16) sM[t] = MsMd[t];
    __syncthreads();
    int node = blockIdx.x * 64 + (t >> 2);
    int h = t & 3;
    if (node >= n) return;
    int beg = rp[node], end = rp[node + 1];
    const float2 xd = *reinterpret_cast<const float2*>(&x[(size_t)node * 2]);
    float ald = xd.x * sM[8 + h] + xd.y * sM[12 + h];
    float ms0 = sM[h], ms1 = sM[4 + h];
    float z = 0.f, sx = 0.f, sy = 0.f;
#pragma unroll 2
    for (int e = beg; e < end; e++) {
        int s = esrc[e];
        float2 xs = *reinterpret_cast<const float2*>(&x[(size_t)s * 2]);
        float al = xs.x * ms0 + xs.y * ms1;
        float w = __expf(lrelu(al + ald));
        z += w;
        sx = fmaf(w, xs.x, sx);
        sy = fmaf(w, xs.y, sy);
    }
    float inv = 1.f / (z + 1e-16f);
    nsum[(size_t)node * 8 + h] = sx * inv;
    nsum[(size_t)node * 8 + 4 + h] = sy * inv;
}

// ---------------- BN1 moment stats: 5 moments per head over nsum ----------------
__global__ void __launch_bounds__(256) k_mstats(const float* __restrict__ nsum,
                                                float* __restrict__ mpart, int n) {
    int t = threadIdx.x;
    float m[20];
#pragma unroll
    for (int j = 0; j < 20; j++) m[j] = 0.f;
    for (int node = blockIdx.x * 256 + t; node < n; node += gridDim.x * 256) {
        float4 a = *reinterpret_cast<const float4*>(&nsum[(size_t)node * 8]);
        float4 b = *reinterpret_cast<const float4*>(&nsum[(size_t)node * 8 + 4]);
        m[0] += a.x; m[1] += b.x; m[2] += a.x * a.x; m[3] += b.x * b.x; m[4] += a.x * b.x;
        m[5] += a.y; m[6] += b.y; m[7] += a.y * a.y; m[8] += b.y * b.y; m[9] += a.y * b.y;
        m[10] += a.z; m[11] += b.z; m[12] += a.z * a.z; m[13] += b.z * b.z; m[14] += a.z * b.z;
        m[15] += a.w; m[16] += b.w; m[17] += a.w * a.w; m[18] += b.w * b.w; m[19] += a.w * b.w;
    }
#pragma unroll
    for (int off = 1; off < 64; off <<= 1)
#pragma unroll
        for (int j = 0; j < 20; j++) m[j] += __shfl_xor(m[j], off);
    __shared__ float ls[4][20];
    if ((t & 63) == 0)
#pragma unroll
        for (int j = 0; j < 20; j++) ls[t >> 6][j] = m[j];
    __syncthreads();
    if (t < 20) mpart[blockIdx.x * 20 + t] = ls[0][t] + ls[1][t] + ls[2][t] + ls[3][t];
}

// ---------------- BN1 finalize: per-channel P,Q,R  (y = elu(P*sx + Q*sy + R)) ----------
__global__ void k_bn1fin(const float* __restrict__ mpart, const float* __restrict__ W1,
                         const float* __restrict__ b1, const float* __restrict__ g1,
                         const float* __restrict__ be1, float4* __restrict__ PQR,
                         int n, int nb) {
    int c = threadIdx.x;
    if (c >= 128) return;
    int h = c >> 5;
    float mx = 0.f, my = 0.f, mxx = 0.f, myy = 0.f, mxy = 0.f;
    for (int b = 0; b < nb; b++) {
        const float* p = &mpart[b * 20 + h * 5];
        mx += p[0]; my += p[1]; mxx += p[2]; myy += p[3]; mxy += p[4];
    }
    float invn = 1.f / (float)n;
    mx *= invn; my *= invn; mxx *= invn; myy *= invn; mxy *= invn;
    float w0 = W1[c], w1 = W1[128 + c], bb = b1[c];
    float mu = w0 * mx + w1 * my + bb;
    float ex2 = w0 * w0 * mxx + w1 * w1 * myy + 2.f * w0 * w1 * mxy
              + 2.f * bb * (w0 * mx + w1 * my) + bb * bb;
    float var = ex2 - mu * mu;
    float A = g1[c] * rsqrtf(var + BN_EPS);
    float B = be1[c] - mu * A;
    PQR[c] = make_float4(A * w0, A * w1, A * bb + B, 0.f);
}

// ---------------- layer 2 node transform: one thread per node, bf16-packed W2 in LDS ----
// Round-12 proven structure (1 node/thread, 64-thread blocks). W2 stored as bf16 channel
// pairs: 4 ds_read_b128 per k instead of 8 -> halves the per-CU LDS-pipe load that bounds
// this kernel. Unpack (lshl/and) rides the idle VALU pipes.
__global__ void __launch_bounds__(64) k_node2f(
        const float* __restrict__ nsum, const float4* __restrict__ PQR,
        const unsigned* __restrict__ W2bf, const float* __restrict__ as2,
        const float* __restrict__ ad2, unsigned* __restrict__ h2bf,
        float* __restrict__ als2, float* __restrict__ ald2, int n) {
    __shared__ unsigned swb[128 * 16];   // 8 KB: [k][c2] bf16 pairs
    __shared__ float4 spqr[128];         // 2 KB
    int t = threadIdx.x;
    for (int i = t; i < 128 * 16; i += 64) swb[i] = W2bf[i];
    for (int i = t; i < 128; i += 64) spqr[i] = PQR[i];
    __syncthreads();
    int node = blockIdx.x * 64 + t;
    if (node >= n) return;
    float4 sx4 = *reinterpret_cast<const float4*>(&nsum[(size_t)node * 8]);
    float4 sy4 = *reinterpret_cast<const float4*>(&nsum[(size_t)node * 8 + 4]);
    float acc[32];
#pragma unroll
    for (int c = 0; c < 32; c++) acc[c] = 0.f;
    const uint4* swb4 = reinterpret_cast<const uint4*>(swb);
    float sxh, syh;
#pragma unroll
    for (int h = 0; h < 4; h++) {
        if (h == 0) { sxh = sx4.x; syh = sy4.x; }
        else if (h == 1) { sxh = sx4.y; syh = sy4.y; }
        else if (h == 2) { sxh = sx4.z; syh = sy4.z; }
        else { sxh = sx4.w; syh = sy4.w; }
        for (int kk = 0; kk < 32; kk++) {
            int k = h * 32 + kk;
            float4 pqr = spqr[k];
            float yk = elu(fmaf(pqr.x, sxh, fmaf(pqr.y, syh, pqr.z)));
#pragma unroll
            for (int q = 0; q < 4; q++) {
                uint4 u = swb4[k * 4 + q];   // channels 8q .. 8q+7 (bf16 pairs)
                acc[q * 8 + 0] = fmaf(yk, bf_lo(u.x), acc[q * 8 + 0]);
                acc[q * 8 + 1] = fmaf(yk, bf_hi(u.x), acc[q * 8 + 1]);
                acc[q * 8 + 2] = fmaf(yk, bf_lo(u.y), acc[q * 8 + 2]);
                acc[q * 8 + 3] = fmaf(yk, bf_hi(u.y), acc[q * 8 + 3]);
                acc[q * 8 + 4] = fmaf(yk, bf_lo(u.z), acc[q * 8 + 4]);
                acc[q * 8 + 5] = fmaf(yk, bf_hi(u.z), acc[q * 8 + 5]);
                acc[q * 8 + 6] = fmaf(yk, bf_lo(u.w), acc[q * 8 + 6]);
                acc[q * 8 + 7] = fmaf(yk, bf_hi(u.w), acc[q * 8 + 7]);
            }
        }
    }
    float ps = 0.f, pd = 0.f;
#pragma unroll
    for (int c = 0; c < 32; c++) {
        ps = fmaf(acc[c], as2[c], ps);
        pd = fmaf(acc[c], ad2[c], pd);
    }
#pragma unroll
    for (int c = 0; c < 16; c++)
        h2bf[(size_t)node * 16 + c] = f2bf_pack(acc[2 * c], acc[2 * c + 1]);
    als2[node] = ps;
    ald2[node] = pd;
}

// ---------------- BN stats: stage 1 (deterministic tree, float4 loads) ----------------
__global__ void k_stats(const float* __restrict__ x, float* __restrict__ partials,
                        int n, int C) {
    int t = threadIdx.x;
    int G4 = C >> 2;
    int c4 = t & (G4 - 1);
    int rr = t / G4;
    int RPB = 256 / G4;
    float sx = 0.f, sy = 0.f, sz = 0.f, sw_ = 0.f;
    float qx = 0.f, qy = 0.f, qz = 0.f, qw = 0.f;
    for (int r = blockIdx.x * RPB + rr; r < n; r += gridDim.x * RPB) {
        float4 v = *reinterpret_cast<const float4*>(&x[(size_t)r * C + 4 * c4]);
        sx += v.x; sy += v.y; sz += v.z; sw_ += v.w;
        qx += v.x * v.x; qy += v.y * v.y; qz += v.z * v.z; qw += v.w * v.w;
    }
    __shared__ float4 ls[256], ls2[256];
    ls[t] = make_float4(sx, sy, sz, sw_);
    ls2[t] = make_float4(qx, qy, qz, qw);
    __syncthreads();
    if (rr == 0) {
        for (int j = 1; j < RPB; j++) {
            float4 a = ls[j * G4 + c4], b = ls2[j * G4 + c4];
            sx += a.x; sy += a.y; sz += a.z; sw_ += a.w;
            qx += b.x; qy += b.y; qz += b.z; qw += b.w;
        }
        *reinterpret_cast<float4*>(&partials[(size_t)blockIdx.x * 2 * C + 4 * c4]) =
            make_float4(sx, sy, sz, sw_);
        *reinterpret_cast<float4*>(&partials[(size_t)blockIdx.x * 2 * C + C + 4 * c4]) =
            make_float4(qx, qy, qz, qw);
    }
}
// ---------------- BN stats stage 2: parallel finalize (512 threads) ----------------
__global__ void k_stats2(const float* __restrict__ partials, const float* __restrict__ gamma,
                         const float* __restrict__ beta, float* __restrict__ AB,
                         int n, int C, int nb) {
    __shared__ float ls[512], ls2[512];
    int t = threadIdx.x;
    int R = 512 / C;
    int c = t & (C - 1);
    int r = t / C;
    float s = 0.f, s2 = 0.f;
    for (int b = r; b < nb; b += R) {
        s += partials[(size_t)b * 2 * C + c];
        s2 += partials[(size_t)b * 2 * C + C + c];
    }
    ls[t] = s;
    ls2[t] = s2;
    __syncthreads();
    for (int step = R >> 1; step > 0; step >>= 1) {
        if (r < step) {
            ls[t] += ls[t + step * C];
            ls2[t] += ls2[t + step * C];
        }
        __syncthreads();
    }
    if (r == 0) {
        float mu = ls[t] / n;
        float var = ls2[t] / n - mu * mu;
        float inv = rsqrtf(var + BN_EPS);
        float A = gamma[c] * inv;
        AB[c] = A;
        AB[C + c] = beta[c] - mu * A;
    }
}

// ---------------- layer 2 aggregation: 8-lane group per dst node, uint2 bf16 gather -------
__global__ void __launch_bounds__(256) k_agg2(
        const unsigned* __restrict__ h2bf, const float* __restrict__ als2,
        const float* __restrict__ ald2, const int* __restrict__ rp,
        const int* __restrict__ esrc, const float* __restrict__ b2,
        float* __restrict__ out, int n) {
    __shared__ int ss2[4][8][9];    // pad 9 -> group broadcasts on disjoint banks
    __shared__ float swv[4][8][9];
    int wslot = threadIdx.x >> 6;
    int lane = threadIdx.x & 63;
    int g = lane >> 3;       // group within wave
    int e = lane & 7;        // lane within group: dwords 2e,2e+1 of the row
    int wid = blockIdx.x * 32 + wslot * 8 + g;
    if (wid >= n) return;
    int beg = rp[wid], end = rp[wid + 1];
    float ad = ald2[wid];
    float a0 = 0.f, a1 = 0.f, a2 = 0.f, a3 = 0.f;
    float z = 0.f;
    const uint2* __restrict__ hrow = reinterpret_cast<const uint2*>(h2bf);
    for (int cb = beg; cb < end; cb += 8) {
        int cnt = end - cb;
        if (cnt > 8) cnt = 8;
        if (e < cnt) {
            int s = esrc[cb + e];
            ss2[wslot][g][e] = s;
            swv[wslot][g][e] = __expf(lrelu(als2[s] + ad));
        }
        int j = 0;
        for (; j + 4 <= cnt; j += 4) {
            int s0 = ss2[wslot][g][j];
            int s1 = ss2[wslot][g][j + 1];
            int s2 = ss2[wslot][g][j + 2];
            int s3 = ss2[wslot][g][j + 3];
            float w0 = swv[wslot][g][j];
            float w1 = swv[wslot][g][j + 1];
            float w2 = swv[wslot][g][j + 2];
            float w3 = swv[wslot][g][j + 3];
            uint2 p0 = hrow[(size_t)s0 * 8 + e];
            uint2 p1 = hrow[(size_t)s1 * 8 + e];
            uint2 p2 = hrow[(size_t)s2 * 8 + e];
            uint2 p3 = hrow[(size_t)s3 * 8 + e];
            z += w0 + w1 + w2 + w3;
            a0 = fmaf(w0, bf_lo(p0.x), a0); a1 = fmaf(w0, bf_hi(p0.x), a1);
            a2 = fmaf(w0, bf_lo(p0.y), a2); a3 = fmaf(w0, bf_hi(p0.y), a3);
            a0 = fmaf(w1, bf_lo(p1.x), a0); a1 = fmaf(w1, bf_hi(p1.x), a1);
            a2 = fmaf(w1, bf_lo(p1.y), a2); a3 = fmaf(w1, bf_hi(p1.y), a3);
            a0 = fmaf(w2, bf_lo(p2.x), a0); a1 = fmaf(w2, bf_hi(p2.x), a1);
            a2 = fmaf(w2, bf_lo(p2.y), a2); a3 = fmaf(w2, bf_hi(p2.y), a3);
            a0 = fmaf(w3, bf_lo(p3.x), a0); a1 = fmaf(w3, bf_hi(p3.x), a1);
            a2 = fmaf(w3, bf_lo(p3.y), a2); a3 = fmaf(w3, bf_hi(p3.y), a3);
        }
        for (; j < cnt; j++) {
            int s = ss2[wslot][g][j];
            float wgt = swv[wslot][g][j];
            z += wgt;
            uint2 p = hrow[(size_t)s * 8 + e];
            a0 = fmaf(wgt, bf_lo(p.x), a0);
            a1 = fmaf(wgt, bf_hi(p.x), a1);
            a2 = fmaf(wgt, bf_lo(p.y), a2);
            a3 = fmaf(wgt, bf_hi(p.y), a3);
        }
    }
    float inv = 1.f / (z + 1e-16f);   // z uniform across the 8-lane group
    const float4 bv = *reinterpret_cast<const float4*>(&b2[4 * e]);
    float4 o = make_float4(a0 * inv + bv.x, a1 * inv + bv.y, a2 * inv + bv.z, a3 * inv + bv.w);
    *reinterpret_cast<float4*>(&out[(size_t)wid * 32 + 4 * e]) = o;
}

// ---------------- BN2+ELU + mean pool + classifier: wave per graph (inline bounds) -------
__global__ void k_pool(const float* __restrict__ x, const float* __restrict__ AB2,
                       const int* __restrict__ batch, const float* __restrict__ Wc,
                       const float* __restrict__ bc, float* __restrict__ out, int n, int G_) {
    int wid = (blockIdx.x * blockDim.x + threadIdx.x) >> 6;
    int lane = threadIdx.x & 63;
    if (wid >= G_) return;
    int lo = 0, hi = n;
    while (lo < hi) {
        int mid = (lo + hi) >> 1;
        if (batch[mid] < wid) lo = mid + 1; else hi = mid;
    }
    int beg = lo;
    hi = n;
    while (lo < hi) {
        int mid = (lo + hi) >> 1;
        if (batch[mid] < wid + 1) lo = mid + 1; else hi = mid;
    }
    int end = lo;
    int half = lane >> 5, f = lane & 31;
    float A = AB2[f], B = AB2[32 + f];
    float acc = 0.f;
    for (int r = beg + half; r < end; r += 2) {
        float v = x[(size_t)r * 32 + f] * A + B;
        acc += elu(v);
    }
    acc += __shfl_xor(acc, 32);
    float cntf = (float)((end - beg) > 1 ? (end - beg) : 1);
    float embv = acc / cntf;
    float p0 = embv * Wc[f * 2], p1 = embv * Wc[f * 2 + 1];
#pragma unroll
    for (int o = 1; o < 32; o <<= 1) {
        p0 += __shfl_xor(p0, o);
        p1 += __shfl_xor(p1, o);
    }
    if (lane == 0) {
        out[wid * 2] = p0 + bc[0];
        out[wid * 2 + 1] = p1 + bc[1];
    }
}

extern "C" void kernel_launch(void* const* d_in, const int* in_sizes, int n_in,
                              void* d_out, int out_size, void* d_ws, size_t ws_size,
                              hipStream_t stream) {
    const float* x = (const float*)d_in[0];
    const int* ei = (const int*)d_in[1];
    const int* batch = (const int*)d_in[2];
    const float* W1 = (const float*)d_in[3];
    const float* as1 = (const float*)d_in[4];
    const float* ad1 = (const float*)d_in[5];
    const float* b1 = (const float*)d_in[6];
    const float* g1 = (const float*)d_in[7];
    const float* be1 = (const float*)d_in[8];
    const float* W2 = (const float*)d_in[9];
    const float* as2 = (const float*)d_in[10];
    const float* ad2 = (const float*)d_in[11];
    const float* b2 = (const float*)d_in[12];
    const float* g2 = (const float*)d_in[13];
    const float* be2 = (const float*)d_in[14];
    const float* Wc = (const float*)d_in[15];
    const float* bc = (const float*)d_in[16];
    float* out = (float*)d_out;

    const int N = in_sizes[0] / 2;
    const int E = in_sizes[1] / 2;
    const int G = out_size / 2;
    const int Etot = E + N;
    const int B = (N + 511) >> 9;     // buckets of 512 dst nodes (<= 256)
    const int CH = (E + P - 1) / P;   // edges per radix block

    // workspace layout
    char* w = (char*)d_ws;
    size_t off = 0;
    auto alloc = [&](size_t bytes) { void* p = w + off; off = (off + bytes + 255) & ~(size_t)255; return p; };
    float* nsum = (float*)alloc((size_t)N * 8 * 4);          // per-node (sx[4], sy[4])
    unsigned* l2buf = (unsigned*)alloc((size_t)N * 50 * 4);  // h2bf + als2 + ald2 + out2
    int* esrc = (int*)alloc((size_t)Etot * 4);
    unsigned* staged = (unsigned*)alloc((size_t)E * 4);
    int* rp = (int*)alloc((size_t)(N + 1) * 4);
    int* ghist = (int*)alloc((size_t)P * BNUM * 4);
    int* goff = (int*)alloc((size_t)P * BNUM * 4);
    int* sbase = (int*)alloc((BNUM + 1) * 4);
    float* partials = (float*)alloc((size_t)STATS_BLOCKS * 256 * 4);
    float* mpart = (float*)alloc((size_t)MB * 20 * 4);
    float* AB2 = (float*)alloc(64 * 4);
    float* MsMd = (float*)alloc(64 * 4);
    float4* PQR = (float4*)alloc(128 * 16);
    unsigned* W2bf = (unsigned*)alloc(2048 * 4);
    unsigned* h2bf = l2buf;                                  // N*16 uints (N x 32 bf16)
    float* als2 = (float*)(l2buf + (size_t)N * 16);          // N floats
    float* ald2 = (float*)(l2buf + (size_t)N * 17);          // N floats
    float* out2 = (float*)(l2buf + (size_t)N * 18);          // N*32 floats

    // 1. tiny preps: factorized attention matrices + bf16 W2 pack
    k_prep<<<1, 64, 0, stream>>>(W1, as1, ad1, MsMd);
    k_packW2<<<8, 256, 0, stream>>>(W2, W2bf);
    // 2. radix pass A: per-block histograms
    k_hist<<<P, 256, 0, stream>>>(ei, ghist, E, CH);
    // 3. radix pass B: bucket-major exclusive scan -> goff, sbase, rp[N]
    k_gscan<<<1, 1024, 0, stream>>>(ghist, goff, sbase, rp, N, E);
    // 4. radix pass C: scatter to block-private ranges
    k_scatter3<<<P, 256, 0, stream>>>(ei, goff, staged, E, CH);
    // 5. per-bucket finalize: rp + esrc (+self loops)
    k_bucket<<<B, 512, 0, stream>>>(staged, sbase, rp, esrc, N);
    // 6. layer 1 aggregation, factorized: only (sx,sy) per head
    k_agg1f<<<(N + 63) / 64, 256, 0, stream>>>(x, rp, esrc, MsMd, nsum, N);
    // 7. BN1 via per-head moments -> per-channel P,Q,R
    k_mstats<<<MB, 256, 0, stream>>>(nsum, mpart, N);
    k_bn1fin<<<1, 128, 0, stream>>>(mpart, W1, b1, g1, be1, PQR, N, MB);
    // 8. layer 2 node transform: one node/thread, bf16 W2 in LDS (half the LDS reads)
    k_node2f<<<(N + 63) / 64, 64, 0, stream>>>(nsum, PQR, W2bf, as2, ad2, h2bf, als2, ald2, N);
    // 9. layer 2 aggregation (8-lane group per node, 4-edge unroll)
    k_agg2<<<(N + 31) / 32, 256, 0, stream>>>(h2bf, als2, ald2, rp, esrc, b2, out2, N);
    // 10. BN2 stats
    k_stats<<<STATS_BLOCKS, 256, 0, stream>>>(out2, partials, N, 32);
    k_stats2<<<1, 512, 0, stream>>>(partials, g2, be2, AB2, N, 32, STATS_BLOCKS);
    // 11. BN2+ELU + pool + classifier (bounds inline)
    k_pool<<<(G * 64 + 255) / 256, 256, 0, stream>>>(out2, AB2, batch, Wc, bc, out, N, G);
}

// Round 16
// 203.419 us; speedup vs baseline: 1.2195x; 1.1310x over previous
//
#include <hip/hip_runtime.h>
#include <hip/hip_bf16.h>
#include <math.h>

#define HEADS 4
#define HID 32
#define EMB 32
#define SLOPE 0.2f
#define BN_EPS 1e-5f
#define STATS_BLOCKS 256
#define MB 128     // moment-stats blocks
#define BNUM 256   // bucket array size (actual B = ceil(N/512) <= 256)
#define P 256      // radix blocks

typedef __attribute__((ext_vector_type(8))) short short8;   // 8 bf16 (4 VGPRs)
typedef __attribute__((ext_vector_type(4))) float fx4;      // 4 fp32 accumulator

__device__ __forceinline__ float lrelu(float x) { return x > 0.f ? x : SLOPE * x; }
__device__ __forceinline__ float elu(float x) { return x > 0.f ? x : expm1f(x); }

// RNE float->bf16 and pack/unpack helpers
__device__ __forceinline__ unsigned f2bf_pack(float a, float b) {
    unsigned ua = __float_as_uint(a);
    unsigned ub = __float_as_uint(b);
    unsigned ra = (ua + 0x7fffu + ((ua >> 16) & 1u)) >> 16;
    unsigned rb = (ub + 0x7fffu + ((ub >> 16) & 1u)) >> 16;
    return ra | (rb << 16);
}
__device__ __forceinline__ float bf_lo(unsigned p) { return __uint_as_float(p << 16); }
__device__ __forceinline__ float bf_hi(unsigned p) { return __uint_as_float(p & 0xffff0000u); }

union BfFrag { unsigned u[4]; short8 v; };

// ---------------- tiny prep: Ms[2][4], Md[2][4] = per-head dot(W1 row, attn vec) ----------------
__global__ void k_prep(const float* __restrict__ W1, const float* __restrict__ as1,
                       const float* __restrict__ ad1, float* __restrict__ MsMd) {
    int t = threadIdx.x;
    if (t >= 16) return;
    int r = (t >> 2) & 1, h = t & 3;
    const float* a = (t >= 8) ? ad1 : as1;
    float s = 0.f;
#pragma unroll
    for (int d = 0; d < 32; d++) s += W1[r * 128 + h * 32 + d] * a[h * 32 + d];
    MsMd[t] = s;
}

// ---------------- pass A: per-block histogram, p-major ghist[p][b] ----------------
__global__ void __launch_bounds__(256) k_hist(const int* __restrict__ ei,
                                              int* __restrict__ ghist, int E_, int CH) {
    __shared__ int h[BNUM];
    int t = threadIdx.x, p = blockIdx.x;
    h[t] = 0;
    __syncthreads();
    int beg = p * CH, end = beg + CH;
    if (end > E_) end = E_;
    for (int e = beg + t; e < end; e += 256) atomicAdd(&h[ei[E_ + e] >> 9], 1);
    __syncthreads();
    ghist[p * BNUM + t] = h[t];  // coalesced
}

// ---------------- pass B: exclusive scan of ghist in bucket-major order ----------------
__global__ void __launch_bounds__(1024) k_gscan(const int* __restrict__ ghist,
                                                int* __restrict__ goff, int* __restrict__ sbase,
                                                int* __restrict__ rp, int N_, int E_) {
    __shared__ int s[1024];
    int t = threadIdx.x;
    const int PER = (BNUM * P) / 1024;  // 64
    int b0 = t >> 2;
    int p0 = (t & 3) * PER;
    int v[PER];
    int sum = 0;
#pragma unroll
    for (int k = 0; k < PER; k++) {
        v[k] = ghist[(p0 + k) * BNUM + b0];
        sum += v[k];
    }
    s[t] = sum;
    __syncthreads();
    for (int off = 1; off < 1024; off <<= 1) {
        int a = (t >= off) ? s[t - off] : 0;
        __syncthreads();
        s[t] += a;
        __syncthreads();
    }
    int run = s[t] - sum;
#pragma unroll
    for (int k = 0; k < PER; k++) {
        if (p0 + k == 0) sbase[b0] = run;
        goff[(p0 + k) * BNUM + b0] = run;
        run += v[k];
    }
    if (t == 0) {
        sbase[BNUM] = E_;
        rp[N_] = E_ + N_;
    }
}

// ---------------- pass C: scatter into block-private per-bucket ranges ----------------
__global__ void __launch_bounds__(256) k_scatter3(const int* __restrict__ ei,
                                                  const int* __restrict__ goff,
                                                  unsigned* __restrict__ staged,
                                                  int E_, int CH) {
    __shared__ int loff[BNUM];
    __shared__ int lpos[BNUM];
    int t = threadIdx.x, p = blockIdx.x;
    loff[t] = goff[p * BNUM + t];
    lpos[t] = 0;
    __syncthreads();
    int beg = p * CH, end = beg + CH;
    if (end > E_) end = E_;
    for (int e = beg + t; e < end; e += 256) {
        int s = ei[e], d = ei[E_ + e];
        int b = d >> 9;
        unsigned pk = ((unsigned)s << 9) | (unsigned)(d & 511);
        int pos = loff[b] + atomicAdd(&lpos[b], 1);
        staged[pos] = pk;
    }
}

// ---------------- per-bucket finalize: count, scan, write rp + esrc (+self loops) -------
__global__ void __launch_bounds__(512) k_bucket(const unsigned* __restrict__ staged,
                                                const int* __restrict__ sbase,
                                                int* __restrict__ rp, int* __restrict__ esrc,
                                                int N_) {
    int b = blockIdx.x;
    int n0 = b << 9;
    int nn = N_ - n0;
    if (nn > 512) nn = 512;
    if (nn <= 0) return;
    __shared__ int lc[512];
    __shared__ int sc[512];
    __shared__ int wpos[512];
    int t = threadIdx.x;
    lc[t] = 0;
    __syncthreads();
    int sb = sbase[b];
    int m = sbase[b + 1] - sb;
    int eb = sb + (b << 9);
    for (int i = t; i < m; i += 512) atomicAdd(&lc[staged[sb + i] & 511], 1);
    __syncthreads();
    sc[t] = lc[t];
    __syncthreads();
    for (int off = 1; off < 512; off <<= 1) {
        int a = (t >= off) ? sc[t - off] : 0;
        __syncthreads();
        sc[t] += a;
        __syncthreads();
    }
    if (t < nn) {
        int r = eb + (sc[t] - lc[t]) + t;
        rp[n0 + t] = r;
        wpos[t] = r;
        esrc[r + lc[t]] = n0 + t;          // self loop at final slot (no atomic)
    }
    __syncthreads();
    for (int i = t; i < m; i += 512) {
        unsigned p = staged[sb + i];
        int q = atomicAdd(&wpos[p & 511], 1);
        esrc[q] = (int)(p >> 9);
    }
}

// ---------------- layer 1 aggregation, FACTORIZED: emit only (sx,sy) per head ----------
__global__ void __launch_bounds__(256) k_agg1f(
        const float* __restrict__ x, const int* __restrict__ rp,
        const int* __restrict__ esrc, const float* __restrict__ MsMd,
        float* __restrict__ nsum, int n) {
    __shared__ float sM[16];
    int t = threadIdx.x;
    if (t < 16) sM[t] = MsMd[t];
    __syncthreads();
    int node = blockIdx.x * 64 + (t >> 2);
    int h = t & 3;
    if (node >= n) return;
    int beg = rp[node], end = rp[node + 1];
    const float2 xd = *reinterpret_cast<const float2*>(&x[(size_t)node * 2]);
    float ald = xd.x * sM[8 + h] + xd.y * sM[12 + h];
    float ms0 = sM[h], ms1 = sM[4 + h];
    float z = 0.f, sx = 0.f, sy = 0.f;
#pragma unroll 2
    for (int e = beg; e < end; e++) {
        int s = esrc[e];
        float2 xs = *reinterpret_cast<const float2*>(&x[(size_t)s * 2]);
        float al = xs.x * ms0 + xs.y * ms1;
        float w = __expf(lrelu(al + ald));
        z += w;
        sx = fmaf(w, xs.x, sx);
        sy = fmaf(w, xs.y, sy);
    }
    float inv = 1.f / (z + 1e-16f);
    nsum[(size_t)node * 8 + h] = sx * inv;
    nsum[(size_t)node * 8 + 4 + h] = sy * inv;
}

// ---------------- BN1 moment stats: 5 moments per head over nsum ----------------
__global__ void __launch_bounds__(256) k_mstats(const float* __restrict__ nsum,
                                                float* __restrict__ mpart, int n) {
    int t = threadIdx.x;
    float m[20];
#pragma unroll
    for (int j = 0; j < 20; j++) m[j] = 0.f;
    for (int node = blockIdx.x * 256 + t; node < n; node += gridDim.x * 256) {
        float4 a = *reinterpret_cast<const float4*>(&nsum[(size_t)node * 8]);
        float4 b = *reinterpret_cast<const float4*>(&nsum[(size_t)node * 8 + 4]);
        m[0] += a.x; m[1] += b.x; m[2] += a.x * a.x; m[3] += b.x * b.x; m[4] += a.x * b.x;
        m[5] += a.y; m[6] += b.y; m[7] += a.y * a.y; m[8] += b.y * b.y; m[9] += a.y * b.y;
        m[10] += a.z; m[11] += b.z; m[12] += a.z * a.z; m[13] += b.z * b.z; m[14] += a.z * b.z;
        m[15] += a.w; m[16] += b.w; m[17] += a.w * a.w; m[18] += b.w * b.w; m[19] += a.w * b.w;
    }
#pragma unroll
    for (int off = 1; off < 64; off <<= 1)
#pragma unroll
        for (int j = 0; j < 20; j++) m[j] += __shfl_xor(m[j], off);
    __shared__ float ls[4][20];
    if ((t & 63) == 0)
#pragma unroll
        for (int j = 0; j < 20; j++) ls[t >> 6][j] = m[j];
    __syncthreads();
    if (t < 20) mpart[blockIdx.x * 20 + t] = ls[0][t] + ls[1][t] + ls[2][t] + ls[3][t];
}

// ---------------- BN1 finalize: per-channel P,Q,R  (y = elu(P*sx + Q*sy + R)) ----------
__global__ void k_bn1fin(const float* __restrict__ mpart, const float* __restrict__ W1,
                         const float* __restrict__ b1, const float* __restrict__ g1,
                         const float* __restrict__ be1, float4* __restrict__ PQR,
                         int n, int nb) {
    int c = threadIdx.x;
    if (c >= 128) return;
    int h = c >> 5;
    float mx = 0.f, my = 0.f, mxx = 0.f, myy = 0.f, mxy = 0.f;
    for (int b = 0; b < nb; b++) {
        const float* p = &mpart[b * 20 + h * 5];
        mx += p[0]; my += p[1]; mxx += p[2]; myy += p[3]; mxy += p[4];
    }
    float invn = 1.f / (float)n;
    mx *= invn; my *= invn; mxx *= invn; myy *= invn; mxy *= invn;
    float w0 = W1[c], w1 = W1[128 + c], bb = b1[c];
    float mu = w0 * mx + w1 * my + bb;
    float ex2 = w0 * w0 * mxx + w1 * w1 * myy + 2.f * w0 * w1 * mxy
              + 2.f * bb * (w0 * mx + w1 * my) + bb * bb;
    float var = ex2 - mu * mu;
    float A = g1[c] * rsqrtf(var + BN_EPS);
    float B = be1[c] - mu * A;
    PQR[c] = make_float4(A * w0, A * w1, A * bb + B, 0.f);
}

// ---------------- layer 2 node transform via MFMA ----------------------------------------
// Per wave: 16-node tile. A = Y[16 x 128] built in registers (yk = elu(P*sx+Q*sy+R), bf16);
// B = W2[128 x 32] as two 16-col tiles (bf16, from L1). 8x mfma_f32_16x16x32_bf16, fp32 acc.
// A-frag: row = lane&15, k = (lane>>4)*8 + j (+32*kblk). B-frag: col = lane&15, same k.
// C/D: col = lane&15, row = (lane>>4)*4 + r  [verified mapping].
__global__ void __launch_bounds__(256) k_node2m(
        const float* __restrict__ nsum, const float4* __restrict__ PQR,
        const float* __restrict__ W2, const float* __restrict__ as2,
        const float* __restrict__ ad2, unsigned* __restrict__ h2bf,
        float* __restrict__ als2, float* __restrict__ ald2, int n) {
    int t = threadIdx.x;
    int wave = t >> 6, lane = t & 63;
    int col = lane & 15;     // A-row (node) for A-build; channel for B/D
    int kgrp = lane >> 4;    // 0..3
    int nb = blockIdx.x * 64 + wave * 16;
    if (nb >= n) return;
    // ---- load this lane's A-row nsum (row = col) ----
    int nodeA = nb + col;
    float4 sx4 = make_float4(0.f, 0.f, 0.f, 0.f), sy4 = sx4;
    if (nodeA < n) {
        sx4 = *reinterpret_cast<const float4*>(&nsum[(size_t)nodeA * 8]);
        sy4 = *reinterpret_cast<const float4*>(&nsum[(size_t)nodeA * 8 + 4]);
    }
    // ---- B fragments (W2 -> bf16), tile1 = cols 0-15, tile2 = cols 16-31 ----
    BfFrag b1f[4], b2f[4];
#pragma unroll
    for (int kblk = 0; kblk < 4; kblk++) {
#pragma unroll
        for (int j = 0; j < 8; j += 2) {
            int k = kblk * 32 + kgrp * 8 + j;
            b1f[kblk].u[j >> 1] = f2bf_pack(W2[k * 32 + col], W2[(k + 1) * 32 + col]);
            b2f[kblk].u[j >> 1] = f2bf_pack(W2[k * 32 + 16 + col], W2[(k + 1) * 32 + 16 + col]);
        }
    }
    fx4 acc1 = {0.f, 0.f, 0.f, 0.f};
    fx4 acc2 = {0.f, 0.f, 0.f, 0.f};
    // ---- K loop: build A fragment on the fly, 2 MFMAs per kblk ----
    float sxh, syh;
#pragma unroll
    for (int kblk = 0; kblk < 4; kblk++) {
        if (kblk == 0) { sxh = sx4.x; syh = sy4.x; }
        else if (kblk == 1) { sxh = sx4.y; syh = sy4.y; }
        else if (kblk == 2) { sxh = sx4.z; syh = sy4.z; }
        else { sxh = sx4.w; syh = sy4.w; }
        BfFrag af;
        float yk[8];
#pragma unroll
        for (int j = 0; j < 8; j++) {
            int k = kblk * 32 + kgrp * 8 + j;
            float4 pqr = PQR[k];
            yk[j] = elu(fmaf(pqr.x, sxh, fmaf(pqr.y, syh, pqr.z)));
        }
#pragma unroll
        for (int j = 0; j < 8; j += 2) af.u[j >> 1] = f2bf_pack(yk[j], yk[j + 1]);
        acc1 = __builtin_amdgcn_mfma_f32_16x16x32_bf16(af.v, b1f[kblk].v, acc1, 0, 0, 0);
        acc2 = __builtin_amdgcn_mfma_f32_16x16x32_bf16(af.v, b2f[kblk].v, acc2, 0, 0, 0);
    }
    // ---- epilogue: logits (16-lane reduce) + bf16 pack (neighbor shfl) ----
    float a2c = as2[col], a2c2 = as2[16 + col];
    float d2c = ad2[col], d2c2 = ad2[16 + col];
#pragma unroll
    for (int r = 0; r < 4; r++) {
        int node = nb + kgrp * 4 + r;
        float v1 = acc1[r], v2 = acc2[r];
        float pS = v1 * a2c + v2 * a2c2;
        float pD = v1 * d2c + v2 * d2c2;
#pragma unroll
        for (int off = 1; off < 16; off <<= 1) {
            pS += __shfl_xor(pS, off);
            pD += __shfl_xor(pD, off);
        }
        float v1n = __shfl_xor(v1, 1);
        float v2n = __shfl_xor(v2, 1);
        if (node < n) {
            if ((col & 1) == 0) {
                h2bf[(size_t)node * 16 + (col >> 1)] = f2bf_pack(v1, v1n);
                h2bf[(size_t)node * 16 + 8 + (col >> 1)] = f2bf_pack(v2, v2n);
            }
            if (col == 0) { als2[node] = pS; ald2[node] = pD; }
        }
    }
}

// ---------------- BN stats: stage 1 (deterministic tree, float4 loads) ----------------
__global__ void k_stats(const float* __restrict__ x, float* __restrict__ partials,
                        int n, int C) {
    int t = threadIdx.x;
    int G4 = C >> 2;
    int c4 = t & (G4 - 1);
    int rr = t / G4;
    int RPB = 256 / G4;
    float sx = 0.f, sy = 0.f, sz = 0.f, sw_ = 0.f;
    float qx = 0.f, qy = 0.f, qz = 0.f, qw = 0.f;
    for (int r = blockIdx.x * RPB + rr; r < n; r += gridDim.x * RPB) {
        float4 v = *reinterpret_cast<const float4*>(&x[(size_t)r * C + 4 * c4]);
        sx += v.x; sy += v.y; sz += v.z; sw_ += v.w;
        qx += v.x * v.x; qy += v.y * v.y; qz += v.z * v.z; qw += v.w * v.w;
    }
    __shared__ float4 ls[256], ls2[256];
    ls[t] = make_float4(sx, sy, sz, sw_);
    ls2[t] = make_float4(qx, qy, qz, qw);
    __syncthreads();
    if (rr == 0) {
        for (int j = 1; j < RPB; j++) {
            float4 a = ls[j * G4 + c4], b = ls2[j * G4 + c4];
            sx += a.x; sy += a.y; sz += a.z; sw_ += a.w;
            qx += b.x; qy += b.y; qz += b.z; qw += b.w;
        }
        *reinterpret_cast<float4*>(&partials[(size_t)blockIdx.x * 2 * C + 4 * c4]) =
            make_float4(sx, sy, sz, sw_);
        *reinterpret_cast<float4*>(&partials[(size_t)blockIdx.x * 2 * C + C + 4 * c4]) =
            make_float4(qx, qy, qz, qw);
    }
}
// ---------------- BN stats stage 2: parallel finalize (512 threads) ----------------
__global__ void k_stats2(const float* __restrict__ partials, const float* __restrict__ gamma,
                         const float* __restrict__ beta, float* __restrict__ AB,
                         int n, int C, int nb) {
    __shared__ float ls[512], ls2[512];
    int t = threadIdx.x;
    int R = 512 / C;
    int c = t & (C - 1);
    int r = t / C;
    float s = 0.f, s2 = 0.f;
    for (int b = r; b < nb; b += R) {
        s += partials[(size_t)b * 2 * C + c];
        s2 += partials[(size_t)b * 2 * C + C + c];
    }
    ls[t] = s;
    ls2[t] = s2;
    __syncthreads();
    for (int step = R >> 1; step > 0; step >>= 1) {
        if (r < step) {
            ls[t] += ls[t + step * C];
            ls2[t] += ls2[t + step * C];
        }
        __syncthreads();
    }
    if (r == 0) {
        float mu = ls[t] / n;
        float var = ls2[t] / n - mu * mu;
        float inv = rsqrtf(var + BN_EPS);
        float A = gamma[c] * inv;
        AB[c] = A;
        AB[C + c] = beta[c] - mu * A;
    }
}

// ---------------- layer 2 aggregation: 8-lane group per dst node, uint2 bf16 gather -------
__global__ void __launch_bounds__(256) k_agg2(
        const unsigned* __restrict__ h2bf, const float* __restrict__ als2,
        const float* __restrict__ ald2, const int* __restrict__ rp,
        const int* __restrict__ esrc, const float* __restrict__ b2,
        float* __restrict__ out, int n) {
    __shared__ int ss2[4][8][9];    // pad 9 -> group broadcasts on disjoint banks
    __shared__ float swv[4][8][9];
    int wslot = threadIdx.x >> 6;
    int lane = threadIdx.x & 63;
    int g = lane >> 3;       // group within wave
    int e = lane & 7;        // lane within group: dwords 2e,2e+1 of the row
    int wid = blockIdx.x * 32 + wslot * 8 + g;
    if (wid >= n) return;
    int beg = rp[wid], end = rp[wid + 1];
    float ad = ald2[wid];
    float a0 = 0.f, a1 = 0.f, a2 = 0.f, a3 = 0.f;
    float z = 0.f;
    const uint2* __restrict__ hrow = reinterpret_cast<const uint2*>(h2bf);
    for (int cb = beg; cb < end; cb += 8) {
        int cnt = end - cb;
        if (cnt > 8) cnt = 8;
        if (e < cnt) {
            int s = esrc[cb + e];
            ss2[wslot][g][e] = s;
            swv[wslot][g][e] = __expf(lrelu(als2[s] + ad));
        }
        int j = 0;
        for (; j + 4 <= cnt; j += 4) {
            int s0 = ss2[wslot][g][j];
            int s1 = ss2[wslot][g][j + 1];
            int s2 = ss2[wslot][g][j + 2];
            int s3 = ss2[wslot][g][j + 3];
            float w0 = swv[wslot][g][j];
            float w1 = swv[wslot][g][j + 1];
            float w2 = swv[wslot][g][j + 2];
            float w3 = swv[wslot][g][j + 3];
            uint2 p0 = hrow[(size_t)s0 * 8 + e];
            uint2 p1 = hrow[(size_t)s1 * 8 + e];
            uint2 p2 = hrow[(size_t)s2 * 8 + e];
            uint2 p3 = hrow[(size_t)s3 * 8 + e];
            z += w0 + w1 + w2 + w3;
            a0 = fmaf(w0, bf_lo(p0.x), a0); a1 = fmaf(w0, bf_hi(p0.x), a1);
            a2 = fmaf(w0, bf_lo(p0.y), a2); a3 = fmaf(w0, bf_hi(p0.y), a3);
            a0 = fmaf(w1, bf_lo(p1.x), a0); a1 = fmaf(w1, bf_hi(p1.x), a1);
            a2 = fmaf(w1, bf_lo(p1.y), a2); a3 = fmaf(w1, bf_hi(p1.y), a3);
            a0 = fmaf(w2, bf_lo(p2.x), a0); a1 = fmaf(w2, bf_hi(p2.x), a1);
            a2 = fmaf(w2, bf_lo(p2.y), a2); a3 = fmaf(w2, bf_hi(p2.y), a3);
            a0 = fmaf(w3, bf_lo(p3.x), a0); a1 = fmaf(w3, bf_hi(p3.x), a1);
            a2 = fmaf(w3, bf_lo(p3.y), a2); a3 = fmaf(w3, bf_hi(p3.y), a3);
        }
        for (; j < cnt; j++) {
            int s = ss2[wslot][g][j];
            float wgt = swv[wslot][g][j];
            z += wgt;
            uint2 p = hrow[(size_t)s * 8 + e];
            a0 = fmaf(wgt, bf_lo(p.x), a0);
            a1 = fmaf(wgt, bf_hi(p.x), a1);
            a2 = fmaf(wgt, bf_lo(p.y), a2);
            a3 = fmaf(wgt, bf_hi(p.y), a3);
        }
    }
    float inv = 1.f / (z + 1e-16f);   // z uniform across the 8-lane group
    const float4 bv = *reinterpret_cast<const float4*>(&b2[4 * e]);
    float4 o = make_float4(a0 * inv + bv.x, a1 * inv + bv.y, a2 * inv + bv.z, a3 * inv + bv.w);
    *reinterpret_cast<float4*>(&out[(size_t)wid * 32 + 4 * e]) = o;
}

// ---------------- BN2+ELU + mean pool + classifier: wave per graph (inline bounds) -------
__global__ void k_pool(const float* __restrict__ x, const float* __restrict__ AB2,
                       const int* __restrict__ batch, const float* __restrict__ Wc,
                       const float* __restrict__ bc, float* __restrict__ out, int n, int G_) {
    int wid = (blockIdx.x * blockDim.x + threadIdx.x) >> 6;
    int lane = threadIdx.x & 63;
    if (wid >= G_) return;
    int lo = 0, hi = n;
    while (lo < hi) {
        int mid = (lo + hi) >> 1;
        if (batch[mid] < wid) lo = mid + 1; else hi = mid;
    }
    int beg = lo;
    hi = n;
    while (lo < hi) {
        int mid = (lo + hi) >> 1;
        if (batch[mid] < wid + 1) lo = mid + 1; else hi = mid;
    }
    int end = lo;
    int half = lane >> 5, f = lane & 31;
    float A = AB2[f], B = AB2[32 + f];
    float acc = 0.f;
    for (int r = beg + half; r < end; r += 2) {
        float v = x[(size_t)r * 32 + f] * A + B;
        acc += elu(v);
    }
    acc += __shfl_xor(acc, 32);
    float cntf = (float)((end - beg) > 1 ? (end - beg) : 1);
    float embv = acc / cntf;
    float p0 = embv * Wc[f * 2], p1 = embv * Wc[f * 2 + 1];
#pragma unroll
    for (int o = 1; o < 32; o <<= 1) {
        p0 += __shfl_xor(p0, o);
        p1 += __shfl_xor(p1, o);
    }
    if (lane == 0) {
        out[wid * 2] = p0 + bc[0];
        out[wid * 2 + 1] = p1 + bc[1];
    }
}

extern "C" void kernel_launch(void* const* d_in, const int* in_sizes, int n_in,
                              void* d_out, int out_size, void* d_ws, size_t ws_size,
                              hipStream_t stream) {
    const float* x = (const float*)d_in[0];
    const int* ei = (const int*)d_in[1];
    const int* batch = (const int*)d_in[2];
    const float* W1 = (const float*)d_in[3];
    const float* as1 = (const float*)d_in[4];
    const float* ad1 = (const float*)d_in[5];
    const float* b1 = (const float*)d_in[6];
    const float* g1 = (const float*)d_in[7];
    const float* be1 = (const float*)d_in[8];
    const float* W2 = (const float*)d_in[9];
    const float* as2 = (const float*)d_in[10];
    const float* ad2 = (const float*)d_in[11];
    const float* b2 = (const float*)d_in[12];
    const float* g2 = (const float*)d_in[13];
    const float* be2 = (const float*)d_in[14];
    const float* Wc = (const float*)d_in[15];
    const float* bc = (const float*)d_in[16];
    float* out = (float*)d_out;

    const int N = in_sizes[0] / 2;
    const int E = in_sizes[1] / 2;
    const int G = out_size / 2;
    const int Etot = E + N;
    const int B = (N + 511) >> 9;     // buckets of 512 dst nodes (<= 256)
    const int CH = (E + P - 1) / P;   // edges per radix block

    // workspace layout
    char* w = (char*)d_ws;
    size_t off = 0;
    auto alloc = [&](size_t bytes) { void* p = w + off; off = (off + bytes + 255) & ~(size_t)255; return p; };
    float* nsum = (float*)alloc((size_t)N * 8 * 4);          // per-node (sx[4], sy[4])
    unsigned* l2buf = (unsigned*)alloc((size_t)N * 50 * 4);  // h2bf + als2 + ald2 + out2
    int* esrc = (int*)alloc((size_t)Etot * 4);
    unsigned* staged = (unsigned*)alloc((size_t)E * 4);
    int* rp = (int*)alloc((size_t)(N + 1) * 4);
    int* ghist = (int*)alloc((size_t)P * BNUM * 4);
    int* goff = (int*)alloc((size_t)P * BNUM * 4);
    int* sbase = (int*)alloc((BNUM + 1) * 4);
    float* partials = (float*)alloc((size_t)STATS_BLOCKS * 256 * 4);
    float* mpart = (float*)alloc((size_t)MB * 20 * 4);
    float* AB2 = (float*)alloc(64 * 4);
    float* MsMd = (float*)alloc(64 * 4);
    float4* PQR = (float4*)alloc(128 * 16);
    unsigned* h2bf = l2buf;                                  // N*16 uints (N x 32 bf16)
    float* als2 = (float*)(l2buf + (size_t)N * 16);          // N floats
    float* ald2 = (float*)(l2buf + (size_t)N * 17);          // N floats
    float* out2 = (float*)(l2buf + (size_t)N * 18);          // N*32 floats

    // 1. tiny prep: factorized attention matrices
    k_prep<<<1, 64, 0, stream>>>(W1, as1, ad1, MsMd);
    // 2. radix pass A: per-block histograms
    k_hist<<<P, 256, 0, stream>>>(ei, ghist, E, CH);
    // 3. radix pass B: bucket-major exclusive scan -> goff, sbase, rp[N]
    k_gscan<<<1, 1024, 0, stream>>>(ghist, goff, sbase, rp, N, E);
    // 4. radix pass C: scatter to block-private ranges
    k_scatter3<<<P, 256, 0, stream>>>(ei, goff, staged, E, CH);
    // 5. per-bucket finalize: rp + esrc (+self loops)
    k_bucket<<<B, 512, 0, stream>>>(staged, sbase, rp, esrc, N);
    // 6. layer 1 aggregation, factorized: only (sx,sy) per head
    k_agg1f<<<(N + 63) / 64, 256, 0, stream>>>(x, rp, esrc, MsMd, nsum, N);
    // 7. BN1 via per-head moments -> per-channel P,Q,R
    k_mstats<<<MB, 256, 0, stream>>>(nsum, mpart, N);
    k_bn1fin<<<1, 128, 0, stream>>>(mpart, W1, b1, g1, be1, PQR, N, MB);
    // 8. layer 2 node transform: MFMA (16-node tile per wave, 64 nodes per block)
    k_node2m<<<(N + 63) / 64, 256, 0, stream>>>(nsum, PQR, W2, as2, ad2, h2bf, als2, ald2, N);
    // 9. layer 2 aggregation (8-lane group per node, 4-edge unroll)
    k_agg2<<<(N + 31) / 32, 256, 0, stream>>>(h2bf, als2, ald2, rp, esrc, b2, out2, N);
    // 10. BN2 stats
    k_stats<<<STATS_BLOCKS, 256, 0, stream>>>(out2, partials, N, 32);
    k_stats2<<<1, 512, 0, stream>>>(partials, g2, be2, AB2, N, 32, STATS_BLOCKS);
    // 11. BN2+ELU + pool + classifier (bounds inline)
    k_pool<<<(G * 64 + 255) / 256, 256, 0, stream>>>(out2, AB2, batch, Wc, bc, out, N, G);
}